// Round 1
// baseline (317.307 us; speedup 1.0000x reference)
//
#include <hip/hip_runtime.h>
#include <hip/hip_bf16.h>

typedef __attribute__((ext_vector_type(8))) short bf16x8s;   // 8 bf16 as shorts (MFMA frag)
typedef __attribute__((ext_vector_type(4))) float f32x4;
typedef __attribute__((ext_vector_type(4))) __bf16 bf16x4;
typedef __attribute__((ext_vector_type(8))) __bf16 bf16x8;

typedef const __attribute__((address_space(1))) void gvoid_t;
typedef __attribute__((address_space(3))) void lvoid_t;

constexpr int Bc = 2, Tc = 2048, Dc = 1024, Hc = 16, HDc = 64;
constexpr int Mc = Bc * Tc;  // 4096

// ---------------- fp32 -> bf16 convert (exact-grid, 4 elems/thread) ----------------
__global__ void cvt_kernel(const float* __restrict__ in, __bf16* __restrict__ out) {
  int i = (blockIdx.x * blockDim.x + threadIdx.x) * 4;
  float4 v = *(const float4*)(in + i);
  bf16x4 o;
  o[0] = (__bf16)v.x; o[1] = (__bf16)v.y; o[2] = (__bf16)v.z; o[3] = (__bf16)v.w;
  *(bf16x4*)(out + i) = o;
}

// ---------------- GEMM: C[m][e] = sum_d A[m][d] * W[e][d]  (both K-contiguous) -----
// MODE 0: scatter bf16 output into [B,H,T,HD] (per blockIdx.z matrix)
// MODE 1: fp32 row-major [M,N] output
template <int MODE>
__launch_bounds__(256, 2)
__global__ void gemm_kernel(const __bf16* __restrict__ A,
                            const __bf16* __restrict__ W,
                            __bf16* __restrict__ outb,
                            float* __restrict__ outf) {
  __shared__ __bf16 Alds[128 * 64];
  __shared__ __bf16 Blds[128 * 64];
  const int tid = threadIdx.x;
  const int lane = tid & 63, wid = tid >> 6;
  const int wr = wid >> 1, wc = wid & 1;
  const int lr = lane & 15, lg = lane >> 4;
  const int brow = blockIdx.y * 128, bcol = blockIdx.x * 128;
  const __bf16* Wm = W + (size_t)blockIdx.z * (Dc * Dc);

  f32x4 acc[4][4] = {};

  const char* Ag = (const char*)(A + (size_t)brow * Dc);
  const char* Bg = (const char*)(Wm + (size_t)bcol * Dc);
  const int r0 = tid >> 3;          // chunk j = i*256+tid; row = i*32 + (tid>>3)
  const int cb = (tid & 7) * 16;    // byte col within 128B row

  for (int k0 = 0; k0 < Dc; k0 += 64) {
#pragma unroll
    for (int i = 0; i < 4; ++i) {
      const int r = i * 32 + r0;
      const int ldsoff = (i * 256 + wid * 64) * 16;  // wave-uniform base; HW adds lane*16
      __builtin_amdgcn_global_load_lds(
          (gvoid_t*)(Ag + (size_t)r * (Dc * 2) + k0 * 2 + cb),
          (lvoid_t*)((char*)Alds + ldsoff), 16, 0, 0);
      __builtin_amdgcn_global_load_lds(
          (gvoid_t*)(Bg + (size_t)r * (Dc * 2) + k0 * 2 + cb),
          (lvoid_t*)((char*)Blds + ldsoff), 16, 0, 0);
    }
    __syncthreads();
#pragma unroll
    for (int kk = 0; kk < 2; ++kk) {
      const int col = kk * 32 + lg * 8;
      bf16x8s af[4], bfv[4];
#pragma unroll
      for (int m = 0; m < 4; ++m)
        af[m] = *(const bf16x8s*)(Alds + (wr * 64 + m * 16 + lr) * 64 + col);
#pragma unroll
      for (int n = 0; n < 4; ++n)
        bfv[n] = *(const bf16x8s*)(Blds + (wc * 64 + n * 16 + lr) * 64 + col);
#pragma unroll
      for (int m = 0; m < 4; ++m)
#pragma unroll
        for (int n = 0; n < 4; ++n)
          acc[m][n] = __builtin_amdgcn_mfma_f32_16x16x32_bf16(af[m], bfv[n], acc[m][n], 0, 0, 0);
    }
    __syncthreads();
  }

  if (MODE == 0) {
    __bf16* dst = outb + (size_t)blockIdx.z * ((size_t)Mc * Dc);
#pragma unroll
    for (int m = 0; m < 4; ++m) {
#pragma unroll
      for (int j = 0; j < 4; ++j) {
        const int gm = brow + wr * 64 + m * 16 + lg * 4 + j;
        const int b = gm >> 11, t = gm & (Tc - 1);
#pragma unroll
        for (int n = 0; n < 4; ++n) {
          const int gn = bcol + wc * 64 + n * 16 + lr;
          const int h = gn >> 6, hd = gn & 63;
          dst[(((size_t)b * Hc + h) * Tc + t) * HDc + hd] = (__bf16)acc[m][n][j];
        }
      }
    }
  } else {
#pragma unroll
    for (int m = 0; m < 4; ++m) {
#pragma unroll
      for (int j = 0; j < 4; ++j) {
        const int gm = brow + wr * 64 + m * 16 + lg * 4 + j;
#pragma unroll
        for (int n = 0; n < 4; ++n) {
          const int gn = bcol + wc * 64 + n * 16 + lr;
          outf[(size_t)gm * Dc + gn] = acc[m][n][j];
        }
      }
    }
  }
}

// ---------------- RoPE in-place on Q,K in [B,H,T,HD] layout ----------------
// q'[i]    = q[i]*cos[i]    - q[i+32]*sin[i]      (i in [0,32))
// q'[i+32] = q[i+32]*cos[i+32] + q[i]*sin[i+32]
__global__ void rope_kernel(__bf16* __restrict__ q, __bf16* __restrict__ k,
                            const float* __restrict__ cb, const float* __restrict__ sb) {
  const int idx = blockIdx.x * blockDim.x + threadIdx.x;  // B*H*T*32 threads
  const int i = idx & 31;
  const int t = (idx >> 5) & (Tc - 1);
  const int bh = idx >> 16;            // 32*2048 = 65536 per (b,h)
  const int b = bh >> 4;
  const size_t qo = ((size_t)bh * Tc + t) * HDc + i;
  const size_t co = ((size_t)b * Tc + t) * HDc + i;
  const float c0 = cb[co], s0 = sb[co], c1 = cb[co + 32], s1 = sb[co + 32];
  const float a0 = (float)q[qo], a1 = (float)q[qo + 32];
  q[qo]      = (__bf16)(a0 * c0 - a1 * s0);
  q[qo + 32] = (__bf16)(a1 * c1 + a0 * s1);
  const float b0 = (float)k[qo], b1 = (float)k[qo + 32];
  k[qo]      = (__bf16)(b0 * c0 - b1 * s0);
  k[qo + 32] = (__bf16)(b1 * c1 + b0 * s1);
}

// ---------------- V transpose: [B,H,T,HD] -> [B,H,HD,T] ----------------
__global__ void transpose_v(const __bf16* __restrict__ v, __bf16* __restrict__ vt) {
  __shared__ __bf16 tile[64][72];  // +8 pad breaks bank-conflict stride
  const int bh = blockIdx.y, t0 = blockIdx.x * 64;
  const int tid = threadIdx.x;
  const int r = tid >> 2, c0 = (tid & 3) * 16;
  const __bf16* src = v + ((size_t)bh * Tc + t0) * HDc;
  bf16x8 v0 = *(const bf16x8*)(src + r * HDc + c0);
  bf16x8 v1 = *(const bf16x8*)(src + r * HDc + c0 + 8);
#pragma unroll
  for (int u = 0; u < 8; ++u) { tile[r][c0 + u] = v0[u]; tile[r][c0 + 8 + u] = v1[u]; }
  __syncthreads();
  __bf16* dst = vt + ((size_t)bh * HDc + r) * Tc + t0 + (tid & 3) * 16;
  bf16x8 o0, o1;
#pragma unroll
  for (int u = 0; u < 8; ++u) {
    o0[u] = tile[(tid & 3) * 16 + u][r];
    o1[u] = tile[(tid & 3) * 16 + 8 + u][r];
  }
  *(bf16x8*)(dst) = o0;
  *(bf16x8*)(dst + 8) = o1;
}

// ---------------- causal flash attention ----------------
// grid: x = q-block (T/64, reversed for balance), y = b*H+h. 4 waves x 16 q-rows.
__launch_bounds__(256, 2)
__global__ void attn_kernel(const __bf16* __restrict__ Q, const __bf16* __restrict__ K,
                            const __bf16* __restrict__ Vt, __bf16* __restrict__ O) {
  __shared__ __bf16 p_lds[4][16 * 64];
  const int qb = (int)gridDim.x - 1 - (int)blockIdx.x;
  const int bh = blockIdx.y;
  const int lane = threadIdx.x & 63, wid = threadIdx.x >> 6;
  const int lr = lane & 15, lg = lane >> 4;
  const int q0 = qb * 64 + wid * 16;
  const __bf16* Qp = Q + (size_t)bh * Tc * HDc;
  const __bf16* Kp = K + (size_t)bh * Tc * HDc;
  const __bf16* Vp = Vt + (size_t)bh * HDc * Tc;

  const bf16x8s qf0 = *(const bf16x8s*)(Qp + (q0 + lr) * HDc + lg * 8);
  const bf16x8s qf1 = *(const bf16x8s*)(Qp + (q0 + lr) * HDc + 32 + lg * 8);

  f32x4 acc[4] = {};
  float mrow[4] = {-__builtin_inff(), -__builtin_inff(), -__builtin_inff(), -__builtin_inff()};
  float lrow[4] = {0.f, 0.f, 0.f, 0.f};
  const float sc = 0.18033688011112042f;  // (1/8) * log2(e); softmax done in exp2 domain

  __bf16* pl = p_lds[wid];

  for (int it = 0; it <= qb; ++it) {
    const int kv0 = it * 64;
    f32x4 s[4];
#pragma unroll
    for (int ct = 0; ct < 4; ++ct) {
      const bf16x8s kf0 = *(const bf16x8s*)(Kp + (kv0 + ct * 16 + lr) * HDc + lg * 8);
      const bf16x8s kf1 = *(const bf16x8s*)(Kp + (kv0 + ct * 16 + lr) * HDc + 32 + lg * 8);
      f32x4 z = {};
      z = __builtin_amdgcn_mfma_f32_16x16x32_bf16(qf0, kf0, z, 0, 0, 0);
      z = __builtin_amdgcn_mfma_f32_16x16x32_bf16(qf1, kf1, z, 0, 0, 0);
      s[ct] = z;
    }
    const bool mt = (it == qb);  // only the diagonal tile needs masking
    float pm[4];
#pragma unroll
    for (int j = 0; j < 4; ++j) {
      float mx = -__builtin_inff();
#pragma unroll
      for (int ct = 0; ct < 4; ++ct) {
        float v = s[ct][j] * sc;
        if (mt && (kv0 + ct * 16 + lr > q0 + lg * 4 + j)) v = -__builtin_inff();
        s[ct][j] = v;
        mx = fmaxf(mx, v);
      }
      mx = fmaxf(mx, __shfl_xor(mx, 1));
      mx = fmaxf(mx, __shfl_xor(mx, 2));
      mx = fmaxf(mx, __shfl_xor(mx, 4));
      mx = fmaxf(mx, __shfl_xor(mx, 8));
      pm[j] = mx;
    }
#pragma unroll
    for (int j = 0; j < 4; ++j) {
      const float mnew = fmaxf(mrow[j], pm[j]);
      const float alpha = exp2f(mrow[j] - mnew);
      mrow[j] = mnew;
      float rs = 0.f;
#pragma unroll
      for (int ct = 0; ct < 4; ++ct) {
        const float p = exp2f(s[ct][j] - mnew);
        s[ct][j] = p;
        rs += p;
      }
      rs += __shfl_xor(rs, 1);
      rs += __shfl_xor(rs, 2);
      rs += __shfl_xor(rs, 4);
      rs += __shfl_xor(rs, 8);
      lrow[j] = lrow[j] * alpha + rs;
#pragma unroll
      for (int nt = 0; nt < 4; ++nt) acc[nt][j] *= alpha;
    }
    // P (acc layout) -> LDS -> A-frag layout (per-wave region, no barrier needed)
#pragma unroll
    for (int ct = 0; ct < 4; ++ct)
#pragma unroll
      for (int j = 0; j < 4; ++j)
        pl[(lg * 4 + j) * 64 + ct * 16 + lr] = (__bf16)s[ct][j];
#pragma unroll
    for (int kc = 0; kc < 2; ++kc) {
      const bf16x8s pa = *(const bf16x8s*)(pl + lr * 64 + kc * 32 + lg * 8);
#pragma unroll
      for (int nt = 0; nt < 4; ++nt) {
        const bf16x8s vf = *(const bf16x8s*)(Vp + (nt * 16 + lr) * Tc + kv0 + kc * 32 + lg * 8);
        acc[nt] = __builtin_amdgcn_mfma_f32_16x16x32_bf16(pa, vf, acc[nt], 0, 0, 0);
      }
    }
  }
  const int b = bh >> 4, h = bh & 15;
#pragma unroll
  for (int j = 0; j < 4; ++j) {
    const float inv = 1.f / lrow[j];
    const int t = q0 + lg * 4 + j;
    __bf16* dst = O + ((size_t)b * Tc + t) * Dc + h * HDc;
#pragma unroll
    for (int nt = 0; nt < 4; ++nt) dst[nt * 16 + lr] = (__bf16)(acc[nt][j] * inv);
  }
}

// ---------------- launch ----------------
extern "C" void kernel_launch(void* const* d_in, const int* in_sizes, int n_in,
                              void* d_out, int out_size, void* d_ws, size_t ws_size,
                              hipStream_t stream) {
  const float* x  = (const float*)d_in[0];
  const float* cb = (const float*)d_in[1];
  const float* sb = (const float*)d_in[2];
  const float* Wq = (const float*)d_in[3];
  const float* Wk = (const float*)d_in[4];
  const float* Wv = (const float*)d_in[5];
  const float* Wp = (const float*)d_in[6];
  float* out = (float*)d_out;
  char* ws = (char*)d_ws;
  // workspace map (56 MB total):
  //  [0,8)MB   xb   : x as bf16            [M=4096, K=1024]
  //  [8,16)MB  wb   : Wq,Wk,Wv,Wp bf16     4 x [1024,1024]
  //  [16,40)MB qkv  : Q,K,V bf16           3 x [B,H,T,HD]
  //  [40,48)MB vt   : V^T bf16             [B,H,HD,T]
  //  [48,56)MB ao   : attention out bf16   [B,T,D]
  __bf16* xb = (__bf16*)(ws);
  __bf16* wb = (__bf16*)(ws + (8u << 20));
  __bf16* qb = (__bf16*)(ws + (16u << 20));
  __bf16* vt = (__bf16*)(ws + (40u << 20));
  __bf16* ao = (__bf16*)(ws + (48u << 20));
  __bf16* kb = qb + (size_t)Mc * Dc;
  __bf16* vb = kb + (size_t)Mc * Dc;

  cvt_kernel<<<4096, 256, 0, stream>>>(x, xb);                    // 4M elems
  cvt_kernel<<<1024, 256, 0, stream>>>(Wq, wb);                   // 1M each
  cvt_kernel<<<1024, 256, 0, stream>>>(Wk, wb + (1u << 20));
  cvt_kernel<<<1024, 256, 0, stream>>>(Wv, wb + (2u << 20));
  cvt_kernel<<<1024, 256, 0, stream>>>(Wp, wb + (3u << 20));

  gemm_kernel<0><<<dim3(8, 32, 3), 256, 0, stream>>>(xb, wb, qb, nullptr);
  rope_kernel<<<8192, 256, 0, stream>>>(qb, kb, cb, sb);
  transpose_v<<<dim3(32, 32), 256, 0, stream>>>(vb, vt);
  attn_kernel<<<dim3(32, 32), 256, 0, stream>>>(qb, kb, vt, ao);
  gemm_kernel<1><<<dim3(8, 32, 1), 256, 0, stream>>>(ao, wb + (3u << 20), nullptr, out);
}

// Round 2
// 165.289 us; speedup vs baseline: 1.9197x; 1.9197x over previous
//
#include <hip/hip_runtime.h>
#include <hip/hip_bf16.h>

typedef __attribute__((ext_vector_type(8))) short bf16x8s;   // 8 bf16 as shorts (MFMA frag)
typedef __attribute__((ext_vector_type(4))) float f32x4;
typedef __attribute__((ext_vector_type(4))) __bf16 bf16x4;
typedef __attribute__((ext_vector_type(8))) __bf16 bf16x8;

typedef const __attribute__((address_space(1))) void gvoid_t;
typedef __attribute__((address_space(3))) void lvoid_t;

constexpr int Bc = 2, Tc = 2048, Dc = 1024, Hc = 16, HDc = 64;
constexpr int Mc = Bc * Tc;  // 4096

// ---------------- fp32 -> bf16 convert (exact-grid, 4 elems/thread) ----------------
__global__ void cvt_kernel(const float* __restrict__ in, __bf16* __restrict__ out) {
  int i = (blockIdx.x * blockDim.x + threadIdx.x) * 4;
  float4 v = *(const float4*)(in + i);
  bf16x4 o;
  o[0] = (__bf16)v.x; o[1] = (__bf16)v.y; o[2] = (__bf16)v.z; o[3] = (__bf16)v.w;
  *(bf16x4*)(out + i) = o;
}

// fused weight convert: blockIdx.y selects the matrix (4 x 1M elems)
__global__ void cvtw_kernel(const float* __restrict__ a, const float* __restrict__ b,
                            const float* __restrict__ c, const float* __restrict__ d,
                            __bf16* __restrict__ out) {
  const float* srcs[4] = {a, b, c, d};
  const float* src = srcs[blockIdx.y];
  int i = (blockIdx.x * blockDim.x + threadIdx.x) * 4;
  float4 v = *(const float4*)(src + i);
  bf16x4 o;
  o[0] = (__bf16)v.x; o[1] = (__bf16)v.y; o[2] = (__bf16)v.z; o[3] = (__bf16)v.w;
  *(bf16x4*)(out + (size_t)blockIdx.y * (Dc * Dc) + i) = o;
}

// ---------------- GEMM: C[m][e] = sum_d A[m][d] * W[e][d]  (both K-contiguous) -----
template <int MODE>
__launch_bounds__(256, 2)
__global__ void gemm_kernel(const __bf16* __restrict__ A,
                            const __bf16* __restrict__ W,
                            __bf16* __restrict__ outb,
                            float* __restrict__ outf) {
  __shared__ __bf16 Alds[128 * 64];
  __shared__ __bf16 Blds[128 * 64];
  const int tid = threadIdx.x;
  const int lane = tid & 63, wid = tid >> 6;
  const int wr = wid >> 1, wc = wid & 1;
  const int lr = lane & 15, lg = lane >> 4;
  const int brow = blockIdx.y * 128, bcol = blockIdx.x * 128;
  const __bf16* Wm = W + (size_t)blockIdx.z * (Dc * Dc);

  f32x4 acc[4][4] = {};

  const char* Ag = (const char*)(A + (size_t)brow * Dc);
  const char* Bg = (const char*)(Wm + (size_t)bcol * Dc);
  const int r0 = tid >> 3;
  const int cb = (tid & 7) * 16;

  for (int k0 = 0; k0 < Dc; k0 += 64) {
#pragma unroll
    for (int i = 0; i < 4; ++i) {
      const int r = i * 32 + r0;
      const int ldsoff = (i * 256 + wid * 64) * 16;
      __builtin_amdgcn_global_load_lds(
          (gvoid_t*)(Ag + (size_t)r * (Dc * 2) + k0 * 2 + cb),
          (lvoid_t*)((char*)Alds + ldsoff), 16, 0, 0);
      __builtin_amdgcn_global_load_lds(
          (gvoid_t*)(Bg + (size_t)r * (Dc * 2) + k0 * 2 + cb),
          (lvoid_t*)((char*)Blds + ldsoff), 16, 0, 0);
    }
    __syncthreads();
#pragma unroll
    for (int kk = 0; kk < 2; ++kk) {
      const int col = kk * 32 + lg * 8;
      bf16x8s af[4], bfv[4];
#pragma unroll
      for (int m = 0; m < 4; ++m)
        af[m] = *(const bf16x8s*)(Alds + (wr * 64 + m * 16 + lr) * 64 + col);
#pragma unroll
      for (int n = 0; n < 4; ++n)
        bfv[n] = *(const bf16x8s*)(Blds + (wc * 64 + n * 16 + lr) * 64 + col);
#pragma unroll
      for (int m = 0; m < 4; ++m)
#pragma unroll
        for (int n = 0; n < 4; ++n)
          acc[m][n] = __builtin_amdgcn_mfma_f32_16x16x32_bf16(af[m], bfv[n], acc[m][n], 0, 0, 0);
    }
    __syncthreads();
  }

  if (MODE == 0) {
    __bf16* dst = outb + (size_t)blockIdx.z * ((size_t)Mc * Dc);
#pragma unroll
    for (int m = 0; m < 4; ++m) {
#pragma unroll
      for (int j = 0; j < 4; ++j) {
        const int gm = brow + wr * 64 + m * 16 + lg * 4 + j;
        const int b = gm >> 11, t = gm & (Tc - 1);
#pragma unroll
        for (int n = 0; n < 4; ++n) {
          const int gn = bcol + wc * 64 + n * 16 + lr;
          const int h = gn >> 6, hd = gn & 63;
          dst[(((size_t)b * Hc + h) * Tc + t) * HDc + hd] = (__bf16)acc[m][n][j];
        }
      }
    }
  } else {
#pragma unroll
    for (int m = 0; m < 4; ++m) {
#pragma unroll
      for (int j = 0; j < 4; ++j) {
        const int gm = brow + wr * 64 + m * 16 + lg * 4 + j;
#pragma unroll
        for (int n = 0; n < 4; ++n) {
          const int gn = bcol + wc * 64 + n * 16 + lr;
          outf[(size_t)gm * Dc + gn] = acc[m][n][j];
        }
      }
    }
  }
}

// ---------------- RoPE in-place on Q,K in [B,H,T,HD] layout ----------------
__global__ void rope_kernel(__bf16* __restrict__ q, __bf16* __restrict__ k,
                            const float* __restrict__ cb, const float* __restrict__ sb) {
  const int idx = blockIdx.x * blockDim.x + threadIdx.x;
  const int i = idx & 31;
  const int t = (idx >> 5) & (Tc - 1);
  const int bh = idx >> 16;
  const int b = bh >> 4;
  const size_t qo = ((size_t)bh * Tc + t) * HDc + i;
  const size_t co = ((size_t)b * Tc + t) * HDc + i;
  const float c0 = cb[co], s0 = sb[co], c1 = cb[co + 32], s1 = sb[co + 32];
  const float a0 = (float)q[qo], a1 = (float)q[qo + 32];
  q[qo]      = (__bf16)(a0 * c0 - a1 * s0);
  q[qo + 32] = (__bf16)(a1 * c1 + a0 * s1);
  const float b0 = (float)k[qo], b1 = (float)k[qo + 32];
  k[qo]      = (__bf16)(b0 * c0 - b1 * s0);
  k[qo + 32] = (__bf16)(b1 * c1 + b0 * s1);
}

// ---------------- V transpose: [B,H,T,HD] -> [B,H,HD,T] ----------------
__global__ void transpose_v(const __bf16* __restrict__ v, __bf16* __restrict__ vt) {
  __shared__ __bf16 tile[64][72];
  const int bh = blockIdx.y, t0 = blockIdx.x * 64;
  const int tid = threadIdx.x;
  const int r = tid >> 2, c0 = (tid & 3) * 16;
  const __bf16* src = v + ((size_t)bh * Tc + t0) * HDc;
  bf16x8 v0 = *(const bf16x8*)(src + r * HDc + c0);
  bf16x8 v1 = *(const bf16x8*)(src + r * HDc + c0 + 8);
#pragma unroll
  for (int u = 0; u < 8; ++u) { tile[r][c0 + u] = v0[u]; tile[r][c0 + 8 + u] = v1[u]; }
  __syncthreads();
  __bf16* dst = vt + ((size_t)bh * HDc + r) * Tc + t0 + (tid & 3) * 16;
  bf16x8 o0, o1;
#pragma unroll
  for (int u = 0; u < 8; ++u) {
    o0[u] = tile[(tid & 3) * 16 + u][r];
    o1[u] = tile[(tid & 3) * 16 + 8 + u][r];
  }
  *(bf16x8*)(dst) = o0;
  *(bf16x8*)(dst + 8) = o1;
}

// ---------------- causal flash attention (v2) ----------------
// 8 waves x 16 q-rows = 128 q rows per block. K/V staged in LDS, double-buffered,
// XOR-swizzled (byte ^= ((row&7)<<4)) with pre-swizzled global_load_lds source.
// Swapped QK^T (mfma(K,Q)) -> per-lane scalar m/l, 2-shuffle row reduce.
__launch_bounds__(512, 2)
__global__ void attn_kernel(const __bf16* __restrict__ Q, const __bf16* __restrict__ K,
                            const __bf16* __restrict__ Vt, __bf16* __restrict__ O) {
  __shared__ __bf16 Klds[2][64 * 64];
  __shared__ __bf16 Vlds[2][64 * 64];
  __shared__ __bf16 Plds[8][16 * 72];   // per-wave P tile, stride 72 (144B, 16B-aligned rows)
  const int qblk = (int)gridDim.x - 1 - (int)blockIdx.x;   // big blocks first
  const int bh = blockIdx.y;
  const int tid = threadIdx.x;
  const int lane = tid & 63, wid = tid >> 6;
  const int lr = lane & 15, lg = lane >> 4;
  const int q0w = qblk * 128 + wid * 16;
  const __bf16* Qp = Q + (size_t)bh * Tc * HDc;
  const char* Kb = (const char*)(K + (size_t)bh * Tc * HDc);
  const char* Vb = (const char*)(Vt + (size_t)bh * HDc * Tc);

  // staging geometry: chunk c = wid*64+lane; row = c>>3 = wid*8+(lane>>3), slot = lane&7
  const int srow = wid * 8 + (lane >> 3);
  const int scol = ((lane & 7) * 16) ^ ((lane >> 3) << 4);  // pre-swizzled source col byte
  const char* vrow = Vb + (size_t)srow * (Tc * 2);

  const int nt = qblk * 2 + 2;               // block-uniform kv-tile count
  const int ksw = (lr & 7) << 4;             // read-side swizzle

  // Q fragments (registers, global/L2 read once)
  const bf16x8s qf0 = *(const bf16x8s*)(Qp + (q0w + lr) * HDc + lg * 8);
  const bf16x8s qf1 = *(const bf16x8s*)(Qp + (q0w + lr) * HDc + 32 + lg * 8);

  __bf16* Pw = &Plds[wid][0];

  f32x4 acc[4] = {};
  float m = -__builtin_inff(), l = 0.f;
  const float sc = 0.18033688011112042f;  // (1/8) * log2(e)

#define STAGE(IT, BUF)                                                                   \
  do {                                                                                   \
    __builtin_amdgcn_global_load_lds((gvoid_t*)(Kb + (size_t)((IT)*64 + srow) * 128 + scol), \
                                     (lvoid_t*)((char*)Klds[BUF] + wid * 1024), 16, 0, 0);   \
    __builtin_amdgcn_global_load_lds((gvoid_t*)(vrow + (IT)*128 + scol),                 \
                                     (lvoid_t*)((char*)Vlds[BUF] + wid * 1024), 16, 0, 0);   \
  } while (0)

  STAGE(0, 0);
  __syncthreads();

  for (int it = 0; it < nt; ++it) {
    if (it + 1 < nt) STAGE(it + 1, (it + 1) & 1);
    const int kv0 = it * 64;
    if (kv0 <= q0w + 15) {  // wave-uniform: this wave has unmasked work in the tile
      const char* Kl = (const char*)Klds[it & 1];
      const char* Vl = (const char*)Vlds[it & 1];
      const bool mt = (kv0 + 63 > q0w);  // diagonal tile for this wave
      float p[4][4];
      float mx = -__builtin_inff();
#pragma unroll
      for (int ct = 0; ct < 4; ++ct) {
        const int rb = (ct * 16 + lr) * 128;
        const bf16x8s kf0 = *(const bf16x8s*)(Kl + rb + ((lg * 16) ^ ksw));
        const bf16x8s kf1 = *(const bf16x8s*)(Kl + rb + ((64 | (lg * 16)) ^ ksw));
        f32x4 z = {};
        z = __builtin_amdgcn_mfma_f32_16x16x32_bf16(kf0, qf0, z, 0, 0, 0);
        z = __builtin_amdgcn_mfma_f32_16x16x32_bf16(kf1, qf1, z, 0, 0, 0);
#pragma unroll
        for (int j = 0; j < 4; ++j) {
          float v = z[j] * sc;
          if (mt && (kv0 + ct * 16 + lg * 4 + j > q0w + lr)) v = -__builtin_inff();
          p[ct][j] = v;
          mx = fmaxf(mx, v);
        }
      }
      mx = fmaxf(mx, __shfl_xor(mx, 16));
      mx = fmaxf(mx, __shfl_xor(mx, 32));
      const float mnew = fmaxf(m, mx);
      if (!__all(mx <= m)) {  // running max grew somewhere: rescale acc
        const float alpha = exp2f(m - mnew);
        f32x4 ab;
#pragma unroll
        for (int j = 0; j < 4; ++j) ab[j] = __shfl(alpha, lg * 4 + j);
#pragma unroll
        for (int ntile = 0; ntile < 4; ++ntile) acc[ntile] *= ab;
        l *= alpha;
      }
      m = mnew;
      float rs = 0.f;
#pragma unroll
      for (int ct = 0; ct < 4; ++ct)
#pragma unroll
        for (int j = 0; j < 4; ++j) {
          const float e = exp2f(p[ct][j] - m);
          p[ct][j] = e;
          rs += e;
        }
      rs += __shfl_xor(rs, 16);
      rs += __shfl_xor(rs, 32);
      l += rs;
      // P -> LDS (per-wave region): 4 x ds_write_b64
#pragma unroll
      for (int ct = 0; ct < 4; ++ct) {
        bf16x4 pb;
#pragma unroll
        for (int j = 0; j < 4; ++j) pb[j] = (__bf16)p[ct][j];
        *(bf16x4*)(Pw + lr * 72 + ct * 16 + lg * 4) = pb;
      }
      // PV
#pragma unroll
      for (int kc = 0; kc < 2; ++kc) {
        const bf16x8s pa = *(const bf16x8s*)(Pw + lr * 72 + kc * 32 + lg * 8);
#pragma unroll
        for (int ntile = 0; ntile < 4; ++ntile) {
          const bf16x8s vf = *(const bf16x8s*)(
              Vl + (ntile * 16 + lr) * 128 + (((kc << 6) | (lg * 16)) ^ ksw));
          acc[ntile] = __builtin_amdgcn_mfma_f32_16x16x32_bf16(pa, vf, acc[ntile], 0, 0, 0);
        }
      }
    }
    __syncthreads();  // drains this wave's stage loads (vmcnt) + guards buffer reuse
  }
#undef STAGE

  const float linv = 1.f / l;
  const int b = bh >> 4, h = bh & 15;
#pragma unroll
  for (int j = 0; j < 4; ++j) {
    const float iv = __shfl(linv, lg * 4 + j);
    const int t = q0w + lg * 4 + j;
    __bf16* dst = O + ((size_t)b * Tc + t) * Dc + h * HDc;
#pragma unroll
    for (int ntile = 0; ntile < 4; ++ntile) dst[ntile * 16 + lr] = (__bf16)(acc[ntile][j] * iv);
  }
}

// ---------------- launch ----------------
extern "C" void kernel_launch(void* const* d_in, const int* in_sizes, int n_in,
                              void* d_out, int out_size, void* d_ws, size_t ws_size,
                              hipStream_t stream) {
  const float* x  = (const float*)d_in[0];
  const float* cb = (const float*)d_in[1];
  const float* sb = (const float*)d_in[2];
  const float* Wq = (const float*)d_in[3];
  const float* Wk = (const float*)d_in[4];
  const float* Wv = (const float*)d_in[5];
  const float* Wp = (const float*)d_in[6];
  float* out = (float*)d_out;
  char* ws = (char*)d_ws;
  __bf16* xb = (__bf16*)(ws);
  __bf16* wb = (__bf16*)(ws + (8u << 20));
  __bf16* qb = (__bf16*)(ws + (16u << 20));
  __bf16* vt = (__bf16*)(ws + (40u << 20));
  __bf16* ao = (__bf16*)(ws + (48u << 20));
  __bf16* kb = qb + (size_t)Mc * Dc;
  __bf16* vb = kb + (size_t)Mc * Dc;

  cvt_kernel<<<4096, 256, 0, stream>>>(x, xb);
  cvtw_kernel<<<dim3(1024, 4), 256, 0, stream>>>(Wq, Wk, Wv, Wp, wb);

  gemm_kernel<0><<<dim3(8, 32, 3), 256, 0, stream>>>(xb, wb, qb, nullptr);
  rope_kernel<<<8192, 256, 0, stream>>>(qb, kb, cb, sb);
  transpose_v<<<dim3(32, 32), 256, 0, stream>>>(vb, vt);
  attn_kernel<<<dim3(16, 32), 512, 0, stream>>>(qb, kb, vt, ao);
  gemm_kernel<1><<<dim3(8, 32, 1), 256, 0, stream>>>(ao, wb + (3u << 20), nullptr, out);
}

// Round 3
// 149.551 us; speedup vs baseline: 2.1217x; 1.1052x over previous
//
#include <hip/hip_runtime.h>
#include <hip/hip_bf16.h>

typedef __attribute__((ext_vector_type(8))) short bf16x8s;   // 8 bf16 as shorts (MFMA frag)
typedef __attribute__((ext_vector_type(4))) float f32x4;
typedef __attribute__((ext_vector_type(4))) __bf16 bf16x4;
typedef __attribute__((ext_vector_type(8))) __bf16 bf16x8;

typedef const __attribute__((address_space(1))) void gvoid_t;
typedef __attribute__((address_space(3))) void lvoid_t;

constexpr int Bc = 2, Tc = 2048, Dc = 1024, Hc = 16, HDc = 64;
constexpr int Mc = Bc * Tc;  // 4096

// ---------------- fp32 -> bf16 convert (exact-grid, 4 elems/thread) ----------------
__global__ void cvt_kernel(const float* __restrict__ in, __bf16* __restrict__ out) {
  int i = (blockIdx.x * blockDim.x + threadIdx.x) * 4;
  float4 v = *(const float4*)(in + i);
  bf16x4 o;
  o[0] = (__bf16)v.x; o[1] = (__bf16)v.y; o[2] = (__bf16)v.z; o[3] = (__bf16)v.w;
  *(bf16x4*)(out + i) = o;
}

// fused weight convert: blockIdx.y selects the matrix (4 x 1M elems)
__global__ void cvtw_kernel(const float* __restrict__ a, const float* __restrict__ b,
                            const float* __restrict__ c, const float* __restrict__ d,
                            __bf16* __restrict__ out) {
  const float* srcs[4] = {a, b, c, d};
  const float* src = srcs[blockIdx.y];
  int i = (blockIdx.x * blockDim.x + threadIdx.x) * 4;
  float4 v = *(const float4*)(src + i);
  bf16x4 o;
  o[0] = (__bf16)v.x; o[1] = (__bf16)v.y; o[2] = (__bf16)v.z; o[3] = (__bf16)v.w;
  *(bf16x4*)(out + (size_t)blockIdx.y * (Dc * Dc) + i) = o;
}

// ---------------- GEMM: C[m][e] = sum_d A[m][d] * W[e][d]  (both K-contiguous) -----
// MODE 0: QKV — z=0: RoPE+score-scale -> [B,H,T,HD]; z=1: RoPE -> [B,H,T,HD];
//               z=2: plain scatter -> [B,H,T,HD]
// MODE 1: fp32 row-major [M,N] output
template <int MODE>
__launch_bounds__(256, 2)
__global__ void gemm_kernel(const __bf16* __restrict__ A,
                            const __bf16* __restrict__ W,
                            __bf16* __restrict__ outb,
                            float* __restrict__ outf,
                            const float* __restrict__ cbt,
                            const float* __restrict__ sbt) {
  __shared__ __bf16 Alds[128 * 64];
  __shared__ __bf16 Blds[128 * 64];
  const int tid = threadIdx.x;
  const int lane = tid & 63, wid = tid >> 6;
  const int wr = wid >> 1, wc = wid & 1;
  const int lr = lane & 15, lg = lane >> 4;
  const int brow = blockIdx.y * 128, bcol = blockIdx.x * 128;
  const __bf16* Wm = W + (size_t)blockIdx.z * (Dc * Dc);

  f32x4 acc[4][4] = {};

  const char* Ag = (const char*)(A + (size_t)brow * Dc);
  const char* Bg = (const char*)(Wm + (size_t)bcol * Dc);
  const int r0 = tid >> 3;
  const int cb = (tid & 7) * 16;

  for (int k0 = 0; k0 < Dc; k0 += 64) {
#pragma unroll
    for (int i = 0; i < 4; ++i) {
      const int r = i * 32 + r0;
      const int ldsoff = (i * 256 + wid * 64) * 16;
      __builtin_amdgcn_global_load_lds(
          (gvoid_t*)(Ag + (size_t)r * (Dc * 2) + k0 * 2 + cb),
          (lvoid_t*)((char*)Alds + ldsoff), 16, 0, 0);
      __builtin_amdgcn_global_load_lds(
          (gvoid_t*)(Bg + (size_t)r * (Dc * 2) + k0 * 2 + cb),
          (lvoid_t*)((char*)Blds + ldsoff), 16, 0, 0);
    }
    __syncthreads();
#pragma unroll
    for (int kk = 0; kk < 2; ++kk) {
      const int col = kk * 32 + lg * 8;
      bf16x8s af[4], bfv[4];
#pragma unroll
      for (int m = 0; m < 4; ++m)
        af[m] = *(const bf16x8s*)(Alds + (wr * 64 + m * 16 + lr) * 64 + col);
#pragma unroll
      for (int n = 0; n < 4; ++n)
        bfv[n] = *(const bf16x8s*)(Blds + (wc * 64 + n * 16 + lr) * 64 + col);
#pragma unroll
      for (int m = 0; m < 4; ++m)
#pragma unroll
        for (int n = 0; n < 4; ++n)
          acc[m][n] = __builtin_amdgcn_mfma_f32_16x16x32_bf16(af[m], bfv[n], acc[m][n], 0, 0, 0);
    }
    __syncthreads();
  }

  if (MODE == 0) {
    const int z = blockIdx.z;
    if (z <= 1) {
      // fused RoPE (+ score scale for Q). Wave's 64 cols = exactly one head.
      const float scl = (z == 0) ? 0.18033688011112042f : 1.0f;  // (1/8)*log2(e)
#pragma unroll
      for (int m = 0; m < 4; ++m) {
#pragma unroll
        for (int j = 0; j < 4; ++j) {
          const int gm = brow + wr * 64 + m * 16 + lg * 4 + j;
          const float* cbase = cbt + (size_t)gm * HDc;  // (b*T+t)*64 == gm*64
          const float* sbase = sbt + (size_t)gm * HDc;
#pragma unroll
          for (int n = 0; n < 2; ++n) {
            const int i = n * 16 + lr;
            const float c0 = cbase[i], s0 = sbase[i];
            const float c1 = cbase[i + 32], s1 = sbase[i + 32];
            const float v0 = acc[m][n][j], v1 = acc[m][n + 2][j];
            acc[m][n][j]     = (v0 * c0 - v1 * s0) * scl;
            acc[m][n + 2][j] = (v1 * c1 + v0 * s1) * scl;
          }
        }
      }
    }
    __bf16* dst = outb + (size_t)z * ((size_t)Mc * Dc);
#pragma unroll
    for (int m = 0; m < 4; ++m) {
#pragma unroll
      for (int j = 0; j < 4; ++j) {
        const int gm = brow + wr * 64 + m * 16 + lg * 4 + j;
        const int b = gm >> 11, t = gm & (Tc - 1);
#pragma unroll
        for (int n = 0; n < 4; ++n) {
          const int gn = bcol + wc * 64 + n * 16 + lr;
          const int h = gn >> 6, hd = gn & 63;
          dst[(((size_t)b * Hc + h) * Tc + t) * HDc + hd] = (__bf16)acc[m][n][j];
        }
      }
    }
  } else {
#pragma unroll
    for (int m = 0; m < 4; ++m) {
#pragma unroll
      for (int j = 0; j < 4; ++j) {
        const int gm = brow + wr * 64 + m * 16 + lg * 4 + j;
#pragma unroll
        for (int n = 0; n < 4; ++n) {
          const int gn = bcol + wc * 64 + n * 16 + lr;
          outf[(size_t)gm * Dc + gn] = acc[m][n][j];
        }
      }
    }
  }
}

// ---------------- V transpose: [B,H,T,HD] -> [B,H,HD,T] ----------------
__global__ void transpose_v(const __bf16* __restrict__ v, __bf16* __restrict__ vt) {
  __shared__ __bf16 tile[64][72];
  const int bh = blockIdx.y, t0 = blockIdx.x * 64;
  const int tid = threadIdx.x;
  const int r = tid >> 2, c0 = (tid & 3) * 16;
  const __bf16* src = v + ((size_t)bh * Tc + t0) * HDc;
  bf16x8 v0 = *(const bf16x8*)(src + r * HDc + c0);
  bf16x8 v1 = *(const bf16x8*)(src + r * HDc + c0 + 8);
#pragma unroll
  for (int u = 0; u < 8; ++u) { tile[r][c0 + u] = v0[u]; tile[r][c0 + 8 + u] = v1[u]; }
  __syncthreads();
  __bf16* dst = vt + ((size_t)bh * HDc + r) * Tc + t0 + (tid & 3) * 16;
  bf16x8 o0, o1;
#pragma unroll
  for (int u = 0; u < 8; ++u) {
    o0[u] = tile[(tid & 3) * 16 + u][r];
    o1[u] = tile[(tid & 3) * 16 + 8 + u][r];
  }
  *(bf16x8*)(dst) = o0;
  *(bf16x8*)(dst + 8) = o1;
}

// ---------------- causal flash attention (v3: counted-vmcnt pipeline) ----------------
// 8 waves x 16 q-rows = 128 q rows per block. K/V double-buffered in LDS,
// XOR-swizzled, staged via global_load_lds with prefetch held in flight ACROSS
// raw s_barriers (s_waitcnt vmcnt(2), never 0 in steady state). Swapped QK^T,
// scalar per-lane m/l, defer-max (THR=8, exp2 domain). Q pre-scaled in GEMM.
// Block mapping groups 4 bh per XCD so K/V re-reads hit the per-XCD L2.
__launch_bounds__(512, 2)
__global__ void attn_kernel(const __bf16* __restrict__ Q, const __bf16* __restrict__ K,
                            const __bf16* __restrict__ Vt, __bf16* __restrict__ O) {
  __shared__ __bf16 Klds[2][64 * 64];
  __shared__ __bf16 Vlds[2][64 * 64];
  __shared__ __bf16 Plds[8][16 * 72];
  // XCD-grouped mapping: XCD x (blocks f ≡ x mod 8) owns bh in [4x, 4x+4)
  const int f = blockIdx.x;
  const int w = (f & 7) * 64 + (f >> 3);
  const int bh = w >> 4;
  const int qblk = w & 15;
  const int tid = threadIdx.x;
  const int lane = tid & 63, wid = tid >> 6;
  const int lr = lane & 15, lg = lane >> 4;
  const int q0w = qblk * 128 + wid * 16;
  const __bf16* Qp = Q + (size_t)bh * Tc * HDc;
  const char* Kb = (const char*)(K + (size_t)bh * Tc * HDc);
  const char* Vb = (const char*)(Vt + (size_t)bh * HDc * Tc);

  // staging geometry: chunk c = wid*64+lane; row = wid*8+(lane>>3), slot = lane&7
  const int srow = wid * 8 + (lane >> 3);
  const int scol = ((lane & 7) * 16) ^ ((lane >> 3) << 4);  // pre-swizzled source col byte
  const char* vrow = Vb + (size_t)srow * (Tc * 2);

  const int nt = qblk * 2 + 2;               // block-uniform kv-tile count
  const int ksw = (lr & 7) << 4;             // read-side swizzle

  const bf16x8s qf0 = *(const bf16x8s*)(Qp + (q0w + lr) * HDc + lg * 8);
  const bf16x8s qf1 = *(const bf16x8s*)(Qp + (q0w + lr) * HDc + 32 + lg * 8);

  __bf16* Pw = &Plds[wid][0];

  f32x4 acc[4] = {};
  float m = -__builtin_inff(), l = 0.f;

#define STAGE(IT, BUF)                                                                       \
  do {                                                                                       \
    __builtin_amdgcn_global_load_lds((gvoid_t*)(Kb + (size_t)((IT)*64 + srow) * 128 + scol), \
                                     (lvoid_t*)((char*)Klds[BUF] + wid * 1024), 16, 0, 0);   \
    __builtin_amdgcn_global_load_lds((gvoid_t*)(vrow + (IT)*128 + scol),                     \
                                     (lvoid_t*)((char*)Vlds[BUF] + wid * 1024), 16, 0, 0);   \
  } while (0)

  STAGE(0, 0);

  for (int it = 0; it < nt; ++it) {
    if (it + 1 < nt) {
      STAGE(it + 1, (it + 1) & 1);
      asm volatile("s_waitcnt vmcnt(2)" ::: "memory");  // tile it landed; it+1 in flight
    } else {
      asm volatile("s_waitcnt vmcnt(0)" ::: "memory");  // last tile: drain
    }
    __builtin_amdgcn_sched_barrier(0);
    __builtin_amdgcn_s_barrier();                       // all waves' tile-it data visible
    __builtin_amdgcn_sched_barrier(0);

    const int kv0 = it * 64;
    if (kv0 <= q0w + 15) {  // wave-uniform participation
      const char* Kl = (const char*)Klds[it & 1];
      const char* Vl = (const char*)Vlds[it & 1];
      const bool mt = (kv0 + 63 > q0w);
      float p[4][4];
      float mx = -__builtin_inff();
      __builtin_amdgcn_s_setprio(1);
#pragma unroll
      for (int ct = 0; ct < 4; ++ct) {
        const int rb = (ct * 16 + lr) * 128;
        const bf16x8s kf0 = *(const bf16x8s*)(Kl + rb + ((lg * 16) ^ ksw));
        const bf16x8s kf1 = *(const bf16x8s*)(Kl + rb + ((64 | (lg * 16)) ^ ksw));
        f32x4 z = {};
        z = __builtin_amdgcn_mfma_f32_16x16x32_bf16(kf0, qf0, z, 0, 0, 0);
        z = __builtin_amdgcn_mfma_f32_16x16x32_bf16(kf1, qf1, z, 0, 0, 0);
#pragma unroll
        for (int j = 0; j < 4; ++j) {
          float v = z[j];
          if (mt && (kv0 + ct * 16 + lg * 4 + j > q0w + lr)) v = -__builtin_inff();
          p[ct][j] = v;
          mx = fmaxf(mx, v);
        }
      }
      __builtin_amdgcn_s_setprio(0);
      mx = fmaxf(mx, __shfl_xor(mx, 16));
      mx = fmaxf(mx, __shfl_xor(mx, 32));
      if (!__all(mx - m <= 8.f)) {  // defer-max: rescale only on real growth
        const float mnew = fmaxf(m, mx);
        const float alpha = exp2f(m - mnew);
        f32x4 ab;
#pragma unroll
        for (int j = 0; j < 4; ++j) ab[j] = __shfl(alpha, lg * 4 + j);
#pragma unroll
        for (int ntile = 0; ntile < 4; ++ntile) acc[ntile] *= ab;
        l *= alpha;
        m = mnew;
      }
      float rs = 0.f;
#pragma unroll
      for (int ct = 0; ct < 4; ++ct)
#pragma unroll
        for (int j = 0; j < 4; ++j) {
          const float e = exp2f(p[ct][j] - m);
          p[ct][j] = e;
          rs += e;
        }
      rs += __shfl_xor(rs, 16);
      rs += __shfl_xor(rs, 32);
      l += rs;
      // P -> LDS (per-wave region): 4 x ds_write_b64
#pragma unroll
      for (int ct = 0; ct < 4; ++ct) {
        bf16x4 pb;
#pragma unroll
        for (int j = 0; j < 4; ++j) pb[j] = (__bf16)p[ct][j];
        *(bf16x4*)(Pw + lr * 72 + ct * 16 + lg * 4) = pb;
      }
      __builtin_amdgcn_s_setprio(1);
#pragma unroll
      for (int kc = 0; kc < 2; ++kc) {
        const bf16x8s pa = *(const bf16x8s*)(Pw + lr * 72 + kc * 32 + lg * 8);
#pragma unroll
        for (int ntile = 0; ntile < 4; ++ntile) {
          const bf16x8s vf = *(const bf16x8s*)(
              Vl + (ntile * 16 + lr) * 128 + (((kc << 6) | (lg * 16)) ^ ksw));
          acc[ntile] = __builtin_amdgcn_mfma_f32_16x16x32_bf16(pa, vf, acc[ntile], 0, 0, 0);
        }
      }
      __builtin_amdgcn_s_setprio(0);
    }
    __builtin_amdgcn_sched_barrier(0);
    __builtin_amdgcn_s_barrier();  // reads of buf[it&1] done before it's re-staged
  }
#undef STAGE

  const float linv = 1.f / l;
  const int b = bh >> 4, h = bh & 15;
#pragma unroll
  for (int j = 0; j < 4; ++j) {
    const float iv = __shfl(linv, lg * 4 + j);
    const int t = q0w + lg * 4 + j;
    __bf16* dst = O + ((size_t)b * Tc + t) * Dc + h * HDc;
#pragma unroll
    for (int ntile = 0; ntile < 4; ++ntile) dst[ntile * 16 + lr] = (__bf16)(acc[ntile][j] * iv);
  }
}

// ---------------- launch ----------------
extern "C" void kernel_launch(void* const* d_in, const int* in_sizes, int n_in,
                              void* d_out, int out_size, void* d_ws, size_t ws_size,
                              hipStream_t stream) {
  const float* x  = (const float*)d_in[0];
  const float* cbt = (const float*)d_in[1];
  const float* sbt = (const float*)d_in[2];
  const float* Wq = (const float*)d_in[3];
  const float* Wk = (const float*)d_in[4];
  const float* Wv = (const float*)d_in[5];
  const float* Wp = (const float*)d_in[6];
  float* out = (float*)d_out;
  char* ws = (char*)d_ws;
  __bf16* xb = (__bf16*)(ws);
  __bf16* wb = (__bf16*)(ws + (8u << 20));
  __bf16* qb = (__bf16*)(ws + (16u << 20));
  __bf16* vt = (__bf16*)(ws + (40u << 20));
  __bf16* ao = (__bf16*)(ws + (48u << 20));
  __bf16* kb = qb + (size_t)Mc * Dc;
  __bf16* vb = kb + (size_t)Mc * Dc;

  cvt_kernel<<<4096, 256, 0, stream>>>(x, xb);
  cvtw_kernel<<<dim3(1024, 4), 256, 0, stream>>>(Wq, Wk, Wv, Wp, wb);

  gemm_kernel<0><<<dim3(8, 32, 3), 256, 0, stream>>>(xb, wb, qb, nullptr, cbt, sbt);
  transpose_v<<<dim3(32, 32), 256, 0, stream>>>(vb, vt);
  attn_kernel<<<512, 512, 0, stream>>>(qb, kb, vt, ao);
  gemm_kernel<1><<<dim3(8, 32, 1), 256, 0, stream>>>(ao, wb + (3u << 20), nullptr, out, nullptr, nullptr);
}

// Round 4
// 132.934 us; speedup vs baseline: 2.3869x; 1.1250x over previous
//
#include <hip/hip_runtime.h>
#include <hip/hip_bf16.h>

typedef __attribute__((ext_vector_type(8))) short bf16x8s;   // 8 bf16 as shorts (MFMA frag)
typedef __attribute__((ext_vector_type(4))) float f32x4;
typedef __attribute__((ext_vector_type(4))) __bf16 bf16x4;
typedef __attribute__((ext_vector_type(8))) __bf16 bf16x8;

typedef const __attribute__((address_space(1))) void gvoid_t;
typedef __attribute__((address_space(3))) void lvoid_t;

constexpr int Bc = 2, Tc = 2048, Dc = 1024, Hc = 16, HDc = 64;
constexpr int Mc = Bc * Tc;  // 4096

// ---------------- fp32 -> bf16 convert (exact-grid, 4 elems/thread) ----------------
__global__ void cvt_kernel(const float* __restrict__ in, __bf16* __restrict__ out) {
  int i = (blockIdx.x * blockDim.x + threadIdx.x) * 4;
  float4 v = *(const float4*)(in + i);
  bf16x4 o;
  o[0] = (__bf16)v.x; o[1] = (__bf16)v.y; o[2] = (__bf16)v.z; o[3] = (__bf16)v.w;
  *(bf16x4*)(out + i) = o;
}

// fused weight convert: blockIdx.y selects the matrix (4 x 1M elems)
__global__ void cvtw_kernel(const float* __restrict__ a, const float* __restrict__ b,
                            const float* __restrict__ c, const float* __restrict__ d,
                            __bf16* __restrict__ out) {
  const float* srcs[4] = {a, b, c, d};
  const float* src = srcs[blockIdx.y];
  int i = (blockIdx.x * blockDim.x + threadIdx.x) * 4;
  float4 v = *(const float4*)(src + i);
  bf16x4 o;
  o[0] = (__bf16)v.x; o[1] = (__bf16)v.y; o[2] = (__bf16)v.z; o[3] = (__bf16)v.w;
  *(bf16x4*)(out + (size_t)blockIdx.y * (Dc * Dc) + i) = o;
}

// ---------------- GEMM: C[m][e] = sum_d A[m][d] * W[e][d]  (both K-contiguous) -----
// Block remap: each XCD (linear%8) owns a 4-row x 8-col chunk -> 1MB A panel +
// 2MB B fit the per-XCD 4MB L2. Requires gridDim.x==8, gridDim.y==32.
// MODE 0: QKV — z=0: RoPE+score-scale; z=1: RoPE; z=2: plain scatter -> [B,H,T,HD]
// MODE 1: fp32 row-major [M,N] output
template <int MODE>
__launch_bounds__(256, 2)
__global__ void gemm_kernel(const __bf16* __restrict__ A,
                            const __bf16* __restrict__ W,
                            __bf16* __restrict__ outb,
                            float* __restrict__ outf,
                            const float* __restrict__ cbt,
                            const float* __restrict__ sbt) {
  __shared__ __bf16 Alds[128 * 64];
  __shared__ __bf16 Blds[128 * 64];
  const int tid = threadIdx.x;
  const int lane = tid & 63, wid = tid >> 6;
  const int wr = wid >> 1, wc = wid & 1;
  const int lr = lane & 15, lg = lane >> 4;
  // XCD-chunked remap (XCD = linear block id % 8 heuristic)
  const int lid = blockIdx.x + (int)gridDim.x * blockIdx.y;
  const int xcd = lid & 7, g = lid >> 3;
  const int brow = (xcd * 4 + (g & 3)) * 128;
  const int bcol = (g >> 2) * 128;
  const __bf16* Wm = W + (size_t)blockIdx.z * (Dc * Dc);

  f32x4 acc[4][4] = {};

  const char* Ag = (const char*)(A + (size_t)brow * Dc);
  const char* Bg = (const char*)(Wm + (size_t)bcol * Dc);
  const int r0 = tid >> 3;
  const int cb = (tid & 7) * 16;

  for (int k0 = 0; k0 < Dc; k0 += 64) {
#pragma unroll
    for (int i = 0; i < 4; ++i) {
      const int r = i * 32 + r0;
      const int ldsoff = (i * 256 + wid * 64) * 16;
      __builtin_amdgcn_global_load_lds(
          (gvoid_t*)(Ag + (size_t)r * (Dc * 2) + k0 * 2 + cb),
          (lvoid_t*)((char*)Alds + ldsoff), 16, 0, 0);
      __builtin_amdgcn_global_load_lds(
          (gvoid_t*)(Bg + (size_t)r * (Dc * 2) + k0 * 2 + cb),
          (lvoid_t*)((char*)Blds + ldsoff), 16, 0, 0);
    }
    __syncthreads();
#pragma unroll
    for (int kk = 0; kk < 2; ++kk) {
      const int col = kk * 32 + lg * 8;
      bf16x8s af[4], bfv[4];
#pragma unroll
      for (int m = 0; m < 4; ++m)
        af[m] = *(const bf16x8s*)(Alds + (wr * 64 + m * 16 + lr) * 64 + col);
#pragma unroll
      for (int n = 0; n < 4; ++n)
        bfv[n] = *(const bf16x8s*)(Blds + (wc * 64 + n * 16 + lr) * 64 + col);
#pragma unroll
      for (int m = 0; m < 4; ++m)
#pragma unroll
        for (int n = 0; n < 4; ++n)
          acc[m][n] = __builtin_amdgcn_mfma_f32_16x16x32_bf16(af[m], bfv[n], acc[m][n], 0, 0, 0);
    }
    __syncthreads();
  }

  if (MODE == 0) {
    const int z = blockIdx.z;
    if (z <= 1) {
      const float scl = (z == 0) ? 0.18033688011112042f : 1.0f;  // (1/8)*log2(e)
#pragma unroll
      for (int m = 0; m < 4; ++m) {
#pragma unroll
        for (int j = 0; j < 4; ++j) {
          const int gm = brow + wr * 64 + m * 16 + lg * 4 + j;
          const float* cbase = cbt + (size_t)gm * HDc;
          const float* sbase = sbt + (size_t)gm * HDc;
#pragma unroll
          for (int n = 0; n < 2; ++n) {
            const int i = n * 16 + lr;
            const float c0 = cbase[i], s0 = sbase[i];
            const float c1 = cbase[i + 32], s1 = sbase[i + 32];
            const float v0 = acc[m][n][j], v1 = acc[m][n + 2][j];
            acc[m][n][j]     = (v0 * c0 - v1 * s0) * scl;
            acc[m][n + 2][j] = (v1 * c1 + v0 * s1) * scl;
          }
        }
      }
    }
    __bf16* dst = outb + (size_t)z * ((size_t)Mc * Dc);
#pragma unroll
    for (int m = 0; m < 4; ++m) {
#pragma unroll
      for (int j = 0; j < 4; ++j) {
        const int gm = brow + wr * 64 + m * 16 + lg * 4 + j;
        const int b = gm >> 11, t = gm & (Tc - 1);
#pragma unroll
        for (int n = 0; n < 4; ++n) {
          const int gn = bcol + wc * 64 + n * 16 + lr;
          const int h = gn >> 6, hd = gn & 63;
          dst[(((size_t)b * Hc + h) * Tc + t) * HDc + hd] = (__bf16)acc[m][n][j];
        }
      }
    }
  } else {
#pragma unroll
    for (int m = 0; m < 4; ++m) {
#pragma unroll
      for (int j = 0; j < 4; ++j) {
        const int gm = brow + wr * 64 + m * 16 + lg * 4 + j;
#pragma unroll
        for (int n = 0; n < 4; ++n) {
          const int gn = bcol + wc * 64 + n * 16 + lr;
          outf[(size_t)gm * Dc + gn] = acc[m][n][j];
        }
      }
    }
  }
}

// ---------------- V transpose: [B,H,T,HD] -> [B,H,HD,T] ----------------
__global__ void transpose_v(const __bf16* __restrict__ v, __bf16* __restrict__ vt) {
  __shared__ __bf16 tile[64][72];
  const int bh = blockIdx.y, t0 = blockIdx.x * 64;
  const int tid = threadIdx.x;
  const int r = tid >> 2, c0 = (tid & 3) * 16;
  const __bf16* src = v + ((size_t)bh * Tc + t0) * HDc;
  bf16x8 v0 = *(const bf16x8*)(src + r * HDc + c0);
  bf16x8 v1 = *(const bf16x8*)(src + r * HDc + c0 + 8);
#pragma unroll
  for (int u = 0; u < 8; ++u) { tile[r][c0 + u] = v0[u]; tile[r][c0 + 8 + u] = v1[u]; }
  __syncthreads();
  __bf16* dst = vt + ((size_t)bh * HDc + r) * Tc + t0 + (tid & 3) * 16;
  bf16x8 o0, o1;
#pragma unroll
  for (int u = 0; u < 8; ++u) {
    o0[u] = tile[(tid & 3) * 16 + u][r];
    o1[u] = tile[(tid & 3) * 16 + 8 + u][r];
  }
  *(bf16x8*)(dst) = o0;
  *(bf16x8*)(dst + 8) = o1;
}

// ---------------- causal flash attention (v4: balanced pairs) ----------------
// 64-row q-tiles, 32 per bh. Each block (4 waves, 256 thr) processes q-tiles
// (p, 31-p) sequentially: (p+1) + (32-p) = 33 kv-tiles for EVERY block —
// perfect load balance over the causal triangle. Counted-vmcnt double-buffered
// K/V staging runs flat across the phase boundary; online-softmax state resets
// at u==p. XCD-grouped bh mapping (4 bh per XCD -> K/V L2-resident).
__launch_bounds__(256, 2)
__global__ void attn_kernel(const __bf16* __restrict__ Q, const __bf16* __restrict__ K,
                            const __bf16* __restrict__ Vt, __bf16* __restrict__ O) {
  __shared__ __bf16 Klds[2][64 * 64];
  __shared__ __bf16 Vlds[2][64 * 64];
  __shared__ __bf16 Plds[4][16 * 72];
  const int f = blockIdx.x;
  const int xcd = f & 7, g = f >> 3;        // 64 blocks per XCD = 4 bh
  const int bh = xcd * 4 + (g >> 4);
  const int p = g & 15;                     // pair id: q-tiles p and 31-p
  const int tid = threadIdx.x;
  const int lane = tid & 63, wid = tid >> 6;
  const int lr = lane & 15, lg = lane >> 4;
  const __bf16* Qp = Q + (size_t)bh * Tc * HDc;
  const char* Kb = (const char*)(K + (size_t)bh * Tc * HDc);
  const char* Vb = (const char*)(Vt + (size_t)bh * HDc * Tc);

  const int qtA = p, qtB = 31 - p;
  const int uA = p;                          // last unit of phase A
  const int NU = 33;                         // (p+1) + (32-p)

  // staging: 2 instrs per matrix per tile; chunk c = i*256+tid; row = i*32+(tid>>3)
  const int r8 = tid >> 3;
  const int scol = ((tid & 7) * 16) ^ ((r8 & 7) << 4);   // pre-swizzled source col byte
  const int ksw = (lr & 7) << 4;                         // read-side swizzle
  const char* vrow0 = Vb + (size_t)r8 * (Tc * 2) + scol;
  const char* vrow1 = Vb + (size_t)(32 + r8) * (Tc * 2) + scol;

  // Q fragments for both phases
  const int q0A = qtA * 64 + wid * 16, q0B = qtB * 64 + wid * 16;
  const bf16x8s qA0 = *(const bf16x8s*)(Qp + (q0A + lr) * HDc + lg * 8);
  const bf16x8s qA1 = *(const bf16x8s*)(Qp + (q0A + lr) * HDc + 32 + lg * 8);
  const bf16x8s qB0 = *(const bf16x8s*)(Qp + (q0B + lr) * HDc + lg * 8);
  const bf16x8s qB1 = *(const bf16x8s*)(Qp + (q0B + lr) * HDc + 32 + lg * 8);

  __bf16* Pw = &Plds[wid][0];
  const int b = bh >> 4, h = bh & 15;

  f32x4 acc[4] = {};
  float m = -__builtin_inff(), l = 0.f;

#define STAGE(IT, BUF)                                                                         \
  do {                                                                                         \
    __builtin_amdgcn_global_load_lds((gvoid_t*)(Kb + (size_t)((IT)*64 + r8) * 128 + scol),     \
                                     (lvoid_t*)((char*)Klds[BUF] + wid * 1024), 16, 0, 0);     \
    __builtin_amdgcn_global_load_lds((gvoid_t*)(Kb + (size_t)((IT)*64 + 32 + r8) * 128 + scol),\
                                     (lvoid_t*)((char*)Klds[BUF] + 4096 + wid * 1024), 16, 0, 0);\
    __builtin_amdgcn_global_load_lds((gvoid_t*)(vrow0 + (IT)*128),                             \
                                     (lvoid_t*)((char*)Vlds[BUF] + wid * 1024), 16, 0, 0);     \
    __builtin_amdgcn_global_load_lds((gvoid_t*)(vrow1 + (IT)*128),                             \
                                     (lvoid_t*)((char*)Vlds[BUF] + 4096 + wid * 1024), 16, 0, 0);\
  } while (0)

  STAGE(0, 0);

  for (int u = 0; u < NU; ++u) {
    const bool phB = (u > uA);
    const int qt = phB ? qtB : qtA;
    const int it = phB ? (u - uA - 1) : u;
    if (u + 1 < NU) {
      const int it1 = (u + 1 > uA) ? (u - uA) : (u + 1);
      STAGE(it1, (u + 1) & 1);
      asm volatile("s_waitcnt vmcnt(4)" ::: "memory");  // unit u landed; u+1 in flight
    } else {
      asm volatile("s_waitcnt vmcnt(0)" ::: "memory");
    }
    __builtin_amdgcn_sched_barrier(0);
    __builtin_amdgcn_s_barrier();
    __builtin_amdgcn_sched_barrier(0);

    const int q0w = qt * 64 + wid * 16;
    const bf16x8s qf0 = phB ? qB0 : qA0;
    const bf16x8s qf1 = phB ? qB1 : qA1;
    const int kv0 = it * 64;
    const char* Kl = (const char*)Klds[u & 1];
    const char* Vl = (const char*)Vlds[u & 1];
    const bool mt = (it == qt);
    float pv[4][4];
    float mx = -__builtin_inff();
    __builtin_amdgcn_s_setprio(1);
#pragma unroll
    for (int ct = 0; ct < 4; ++ct) {
      const int rb = (ct * 16 + lr) * 128;
      const bf16x8s kf0 = *(const bf16x8s*)(Kl + rb + ((lg * 16) ^ ksw));
      const bf16x8s kf1 = *(const bf16x8s*)(Kl + rb + ((64 | (lg * 16)) ^ ksw));
      f32x4 z = {};
      z = __builtin_amdgcn_mfma_f32_16x16x32_bf16(kf0, qf0, z, 0, 0, 0);
      z = __builtin_amdgcn_mfma_f32_16x16x32_bf16(kf1, qf1, z, 0, 0, 0);
#pragma unroll
      for (int j = 0; j < 4; ++j) {
        float v = z[j];
        if (mt && (kv0 + ct * 16 + lg * 4 + j > q0w + lr)) v = -__builtin_inff();
        pv[ct][j] = v;
        mx = fmaxf(mx, v);
      }
    }
    __builtin_amdgcn_s_setprio(0);
    mx = fmaxf(mx, __shfl_xor(mx, 16));
    mx = fmaxf(mx, __shfl_xor(mx, 32));
    if (!__all(mx - m <= 8.f)) {  // defer-max
      const float mnew = fmaxf(m, mx);
      const float alpha = exp2f(m - mnew);
      f32x4 ab;
#pragma unroll
      for (int j = 0; j < 4; ++j) ab[j] = __shfl(alpha, lg * 4 + j);
#pragma unroll
      for (int ntile = 0; ntile < 4; ++ntile) acc[ntile] *= ab;
      l *= alpha;
      m = mnew;
    }
    float rs = 0.f;
#pragma unroll
    for (int ct = 0; ct < 4; ++ct)
#pragma unroll
      for (int j = 0; j < 4; ++j) {
        const float e = exp2f(pv[ct][j] - m);
        pv[ct][j] = e;
        rs += e;
      }
    rs += __shfl_xor(rs, 16);
    rs += __shfl_xor(rs, 32);
    l += rs;
#pragma unroll
    for (int ct = 0; ct < 4; ++ct) {
      bf16x4 pb;
#pragma unroll
      for (int j = 0; j < 4; ++j) pb[j] = (__bf16)pv[ct][j];
      *(bf16x4*)(Pw + lr * 72 + ct * 16 + lg * 4) = pb;
    }
    __builtin_amdgcn_s_setprio(1);
#pragma unroll
    for (int kc = 0; kc < 2; ++kc) {
      const bf16x8s pa = *(const bf16x8s*)(Pw + lr * 72 + kc * 32 + lg * 8);
#pragma unroll
      for (int ntile = 0; ntile < 4; ++ntile) {
        const bf16x8s vf = *(const bf16x8s*)(
            Vl + (ntile * 16 + lr) * 128 + (((kc << 6) | (lg * 16)) ^ ksw));
        acc[ntile] = __builtin_amdgcn_mfma_f32_16x16x32_bf16(pa, vf, acc[ntile], 0, 0, 0);
      }
    }
    __builtin_amdgcn_s_setprio(0);

    if (u == uA || u == NU - 1) {  // finalize this q-tile, reset state
      const float linv = 1.f / l;
#pragma unroll
      for (int j = 0; j < 4; ++j) {
        const float iv = __shfl(linv, lg * 4 + j);
        const int t = q0w + lg * 4 + j;
        __bf16* dst = O + ((size_t)b * Tc + t) * Dc + h * HDc;
#pragma unroll
        for (int ntile = 0; ntile < 4; ++ntile)
          dst[ntile * 16 + lr] = (__bf16)(acc[ntile][j] * iv);
      }
#pragma unroll
      for (int ntile = 0; ntile < 4; ++ntile) acc[ntile] = f32x4{0.f, 0.f, 0.f, 0.f};
      m = -__builtin_inff();
      l = 0.f;
    }
    __builtin_amdgcn_sched_barrier(0);
    __builtin_amdgcn_s_barrier();  // buf[u&1] reads done before re-stage
  }
#undef STAGE
}

// ---------------- launch ----------------
extern "C" void kernel_launch(void* const* d_in, const int* in_sizes, int n_in,
                              void* d_out, int out_size, void* d_ws, size_t ws_size,
                              hipStream_t stream) {
  const float* x  = (const float*)d_in[0];
  const float* cbt = (const float*)d_in[1];
  const float* sbt = (const float*)d_in[2];
  const float* Wq = (const float*)d_in[3];
  const float* Wk = (const float*)d_in[4];
  const float* Wv = (const float*)d_in[5];
  const float* Wp = (const float*)d_in[6];
  float* out = (float*)d_out;
  char* ws = (char*)d_ws;
  __bf16* xb = (__bf16*)(ws);
  __bf16* wb = (__bf16*)(ws + (8u << 20));
  __bf16* qb = (__bf16*)(ws + (16u << 20));
  __bf16* vt = (__bf16*)(ws + (40u << 20));
  __bf16* ao = (__bf16*)(ws + (48u << 20));
  __bf16* kb = qb + (size_t)Mc * Dc;
  __bf16* vb = kb + (size_t)Mc * Dc;

  cvt_kernel<<<4096, 256, 0, stream>>>(x, xb);
  cvtw_kernel<<<dim3(1024, 4), 256, 0, stream>>>(Wq, Wk, Wv, Wp, wb);

  gemm_kernel<0><<<dim3(8, 32, 3), 256, 0, stream>>>(xb, wb, qb, nullptr, cbt, sbt);
  transpose_v<<<dim3(32, 32), 256, 0, stream>>>(vb, vt);
  attn_kernel<<<512, 256, 0, stream>>>(qb, kb, vt, ao);
  gemm_kernel<1><<<dim3(8, 32, 1), 256, 0, stream>>>(ao, wb + (3u << 20), nullptr, out, nullptr, nullptr);
}

// Round 5
// 117.275 us; speedup vs baseline: 2.7057x; 1.1335x over previous
//
#include <hip/hip_runtime.h>
#include <hip/hip_bf16.h>

typedef __attribute__((ext_vector_type(8))) short bf16x8s;   // 8 bf16 as shorts (MFMA frag)
typedef __attribute__((ext_vector_type(4))) float f32x4;
typedef __attribute__((ext_vector_type(4))) __bf16 bf16x4;
typedef __attribute__((ext_vector_type(8))) __bf16 bf16x8;

typedef const __attribute__((address_space(1))) void gvoid_t;
typedef __attribute__((address_space(3))) void lvoid_t;

constexpr int Bc = 2, Tc = 2048, Dc = 1024, Hc = 16, HDc = 64;
constexpr int Mc = Bc * Tc;  // 4096

// ---------------- fused fp32 -> bf16 convert: x (4096 blocks) + 4 weights (4096) ----
__global__ void cvt_all(const float* __restrict__ x,
                        const float* __restrict__ wq, const float* __restrict__ wk,
                        const float* __restrict__ wv, const float* __restrict__ wp,
                        __bf16* __restrict__ xb, __bf16* __restrict__ wb) {
  const int bid = blockIdx.x;
  const float* src;
  __bf16* dst;
  int i;
  if (bid < 4096) {
    src = x; dst = xb; i = (bid * 256 + threadIdx.x) * 4;
  } else {
    const int r = bid - 4096;
    const int w = r >> 10;
    src = (w == 0) ? wq : (w == 1) ? wk : (w == 2) ? wv : wp;
    dst = wb + (size_t)w * (Dc * Dc);
    i = ((r & 1023) * 256 + threadIdx.x) * 4;
  }
  float4 v = *(const float4*)(src + i);
  bf16x4 o;
  o[0] = (__bf16)v.x; o[1] = (__bf16)v.y; o[2] = (__bf16)v.z; o[3] = (__bf16)v.w;
  *(bf16x4*)(dst + i) = o;
}

// ---------------- QKV GEMM: C[m][e] = sum_d A[m][d] * W[e][d] ----------------------
// z=0: RoPE+score-scale -> [B,H,T,HD]; z=1: RoPE -> [B,H,T,HD];
// z=2: V^T epilogue (LDS transpose bounce) -> vt [B,H,HD,T]
__launch_bounds__(256, 2)
__global__ void gemm_qkv(const __bf16* __restrict__ A,
                         const __bf16* __restrict__ W,
                         __bf16* __restrict__ outb,
                         __bf16* __restrict__ vtout,
                         const float* __restrict__ cbt,
                         const float* __restrict__ sbt) {
  __shared__ __bf16 smem[2][128 * 64];
  __bf16* Alds = smem[0];
  __bf16* Blds = smem[1];
  const int tid = threadIdx.x;
  const int lane = tid & 63, wid = tid >> 6;
  const int wr = wid >> 1, wc = wid & 1;
  const int lr = lane & 15, lg = lane >> 4;
  // XCD-chunked remap: each XCD owns 4 M-rows x 8 N-cols (1MB A + 2MB B in its L2)
  const int lid = blockIdx.x + (int)gridDim.x * blockIdx.y;
  const int xcd = lid & 7, g = lid >> 3;
  const int brow = (xcd * 4 + (g & 3)) * 128;
  const int bcol = (g >> 2) * 128;
  const __bf16* Wm = W + (size_t)blockIdx.z * (Dc * Dc);

  f32x4 acc[4][4] = {};

  const char* Ag = (const char*)(A + (size_t)brow * Dc);
  const char* Bg = (const char*)(Wm + (size_t)bcol * Dc);
  const int r0 = tid >> 3;
  const int cb = (tid & 7) * 16;

  for (int k0 = 0; k0 < Dc; k0 += 64) {
#pragma unroll
    for (int i = 0; i < 4; ++i) {
      const int r = i * 32 + r0;
      const int ldsoff = (i * 256 + wid * 64) * 16;
      __builtin_amdgcn_global_load_lds(
          (gvoid_t*)(Ag + (size_t)r * (Dc * 2) + k0 * 2 + cb),
          (lvoid_t*)((char*)Alds + ldsoff), 16, 0, 0);
      __builtin_amdgcn_global_load_lds(
          (gvoid_t*)(Bg + (size_t)r * (Dc * 2) + k0 * 2 + cb),
          (lvoid_t*)((char*)Blds + ldsoff), 16, 0, 0);
    }
    __syncthreads();
#pragma unroll
    for (int kk = 0; kk < 2; ++kk) {
      const int col = kk * 32 + lg * 8;
      bf16x8s af[4], bfv[4];
#pragma unroll
      for (int m = 0; m < 4; ++m)
        af[m] = *(const bf16x8s*)(Alds + (wr * 64 + m * 16 + lr) * 64 + col);
#pragma unroll
      for (int n = 0; n < 4; ++n)
        bfv[n] = *(const bf16x8s*)(Blds + (wc * 64 + n * 16 + lr) * 64 + col);
#pragma unroll
      for (int m = 0; m < 4; ++m)
#pragma unroll
        for (int n = 0; n < 4; ++n)
          acc[m][n] = __builtin_amdgcn_mfma_f32_16x16x32_bf16(af[m], bfv[n], acc[m][n], 0, 0, 0);
    }
    __syncthreads();
  }

  const int z = blockIdx.z;
  if (z == 2) {
    // V^T epilogue: stage C^T halves in LDS, coalesced store to vt [B,H,HD,T]
    const int bb = brow >> 11, t0b = brow & (Tc - 1);
    __bf16* tile_t = smem[0];  // [64][136]
#pragma unroll
    for (int h2 = 0; h2 < 2; ++h2) {
      __syncthreads();
      if (wc == h2) {
#pragma unroll
        for (int n = 0; n < 4; ++n) {
#pragma unroll
          for (int m = 0; m < 4; ++m) {
            bf16x4 pb;
#pragma unroll
            for (int j = 0; j < 4; ++j) pb[j] = (__bf16)acc[m][n][j];
            *(bf16x4*)(tile_t + (n * 16 + lr) * 136 + wr * 64 + m * 16 + lg * 4) = pb;
          }
        }
      }
      __syncthreads();
#pragma unroll
      for (int pass = 0; pass < 4; ++pass) {
        const int r = pass * 16 + (tid >> 4);
        const int c8 = (tid & 15) * 8;
        bf16x8 vvv = *(const bf16x8*)(tile_t + r * 136 + c8);
        const int gn = bcol + h2 * 64 + r;
        const int h = gn >> 6, hd = gn & 63;
        *(bf16x8*)(vtout + (((size_t)bb * Hc + h) * HDc + hd) * Tc + t0b + c8) = vvv;
      }
    }
    return;
  }

  // z==0/1: fused RoPE (+ score scale for Q), scatter to [B,H,T,HD]
  {
    const float scl = (z == 0) ? 0.18033688011112042f : 1.0f;  // (1/8)*log2(e)
#pragma unroll
    for (int m = 0; m < 4; ++m) {
#pragma unroll
      for (int j = 0; j < 4; ++j) {
        const int gm = brow + wr * 64 + m * 16 + lg * 4 + j;
        const float* cbase = cbt + (size_t)gm * HDc;
        const float* sbase = sbt + (size_t)gm * HDc;
#pragma unroll
        for (int n = 0; n < 2; ++n) {
          const int i = n * 16 + lr;
          const float c0 = cbase[i], s0 = sbase[i];
          const float c1 = cbase[i + 32], s1 = sbase[i + 32];
          const float v0 = acc[m][n][j], v1 = acc[m][n + 2][j];
          acc[m][n][j]     = (v0 * c0 - v1 * s0) * scl;
          acc[m][n + 2][j] = (v1 * c1 + v0 * s1) * scl;
        }
      }
    }
    __bf16* dst = outb + (size_t)z * ((size_t)Mc * Dc);
#pragma unroll
    for (int m = 0; m < 4; ++m) {
#pragma unroll
      for (int j = 0; j < 4; ++j) {
        const int gm = brow + wr * 64 + m * 16 + lg * 4 + j;
        const int bb = gm >> 11, t = gm & (Tc - 1);
#pragma unroll
        for (int n = 0; n < 4; ++n) {
          const int gn = bcol + wc * 64 + n * 16 + lr;
          const int h = gn >> 6, hd = gn & 63;
          dst[(((size_t)bb * Hc + h) * Tc + t) * HDc + hd] = (__bf16)acc[m][n][j];
        }
      }
    }
  }
}

// ---------------- output projection GEMM: 128x64 tiles, 512 blocks (2/CU) ----------
__launch_bounds__(256, 2)
__global__ void gemm_proj(const __bf16* __restrict__ A, const __bf16* __restrict__ W,
                          float* __restrict__ outf) {
  __shared__ __bf16 Alds[128 * 64];
  __shared__ __bf16 Blds[64 * 64];
  const int tid = threadIdx.x;
  const int lane = tid & 63, wid = tid >> 6;
  const int lr = lane & 15, lg = lane >> 4;
  const int lid = blockIdx.x + (int)gridDim.x * blockIdx.y;  // 512 blocks
  const int xcd = lid & 7, g = lid >> 3;
  const int brow = (xcd * 4 + (g & 3)) * 128;
  const int bcol = (g >> 2) * 64;
  f32x4 acc[2][4] = {};
  const char* Ag = (const char*)(A + (size_t)brow * Dc);
  const char* Bg = (const char*)(W + (size_t)bcol * Dc);
  const int r0 = tid >> 3;
  const int cb = (tid & 7) * 16;
  for (int k0 = 0; k0 < Dc; k0 += 64) {
#pragma unroll
    for (int i = 0; i < 4; ++i) {
      const int r = i * 32 + r0;
      const int ldsoff = (i * 256 + wid * 64) * 16;
      __builtin_amdgcn_global_load_lds(
          (gvoid_t*)(Ag + (size_t)r * (Dc * 2) + k0 * 2 + cb),
          (lvoid_t*)((char*)Alds + ldsoff), 16, 0, 0);
    }
#pragma unroll
    for (int i = 0; i < 2; ++i) {
      const int r = i * 32 + r0;
      const int ldsoff = (i * 256 + wid * 64) * 16;
      __builtin_amdgcn_global_load_lds(
          (gvoid_t*)(Bg + (size_t)r * (Dc * 2) + k0 * 2 + cb),
          (lvoid_t*)((char*)Blds + ldsoff), 16, 0, 0);
    }
    __syncthreads();
#pragma unroll
    for (int kk = 0; kk < 2; ++kk) {
      const int col = kk * 32 + lg * 8;
      bf16x8s af[2], bfv[4];
#pragma unroll
      for (int m = 0; m < 2; ++m)
        af[m] = *(const bf16x8s*)(Alds + (wid * 32 + m * 16 + lr) * 64 + col);
#pragma unroll
      for (int n = 0; n < 4; ++n)
        bfv[n] = *(const bf16x8s*)(Blds + (n * 16 + lr) * 64 + col);
#pragma unroll
      for (int m = 0; m < 2; ++m)
#pragma unroll
        for (int n = 0; n < 4; ++n)
          acc[m][n] = __builtin_amdgcn_mfma_f32_16x16x32_bf16(af[m], bfv[n], acc[m][n], 0, 0, 0);
    }
    __syncthreads();
  }
#pragma unroll
  for (int m = 0; m < 2; ++m)
#pragma unroll
    for (int j = 0; j < 4; ++j) {
      const int gm = brow + wid * 32 + m * 16 + lg * 4 + j;
#pragma unroll
      for (int n = 0; n < 4; ++n) {
        const int gn = bcol + n * 16 + lr;
        outf[(size_t)gm * Dc + gn] = acc[m][n][j];
      }
    }
}

// ---------------- causal flash attention (v5: 1 barrier/unit, 4-buf pipeline) ------
// 64-row q-tiles, balanced pairs (p, 31-p) = 33 units/block. K/V 4-deep LDS
// buffers, prefetch depth 2, counted vmcnt(8), ONE s_barrier per unit (STAGE(u+2)
// overwrites unit u-2's buffer — two barriers of separation from its last reader).
// Interior units skip all mask VALU; diagonal units coincide with finalize units.
__launch_bounds__(256, 2)
__global__ void attn_kernel(const __bf16* __restrict__ Q, const __bf16* __restrict__ K,
                            const __bf16* __restrict__ Vt, __bf16* __restrict__ O) {
  __shared__ __bf16 Klds[4][64 * 64];
  __shared__ __bf16 Vlds[4][64 * 64];
  __shared__ __bf16 Plds[4][16 * 72];
  const int f = blockIdx.x;
  const int xcd = f & 7, g = f >> 3;        // 64 blocks per XCD = 4 bh
  const int bh = xcd * 4 + (g >> 4);
  const int p = g & 15;                     // pair: q-tiles p and 31-p
  const int tid = threadIdx.x;
  const int lane = tid & 63, wid = tid >> 6;
  const int lr = lane & 15, lg = lane >> 4;
  const __bf16* Qp = Q + (size_t)bh * Tc * HDc;
  const char* Kb = (const char*)(K + (size_t)bh * Tc * HDc);
  const char* Vb = (const char*)(Vt + (size_t)bh * HDc * Tc);

  const int qtB = 31 - p;
  const int uA = p, NU = 33;

  const int r8 = tid >> 3;
  const int scol = ((tid & 7) * 16) ^ ((r8 & 7) << 4);   // pre-swizzled source col
  const int ksw = (lr & 7) << 4;                         // read-side swizzle
  const char* vrow0 = Vb + (size_t)r8 * (Tc * 2) + scol;
  const char* vrow1 = Vb + (size_t)(32 + r8) * (Tc * 2) + scol;

  const int q0A = p * 64 + wid * 16, q0B = qtB * 64 + wid * 16;
  bf16x8s qc0 = *(const bf16x8s*)(Qp + (q0A + lr) * HDc + lg * 8);
  bf16x8s qc1 = *(const bf16x8s*)(Qp + (q0A + lr) * HDc + 32 + lg * 8);
  const bf16x8s qB0 = *(const bf16x8s*)(Qp + (q0B + lr) * HDc + lg * 8);
  const bf16x8s qB1 = *(const bf16x8s*)(Qp + (q0B + lr) * HDc + 32 + lg * 8);
  asm volatile("s_waitcnt vmcnt(0)" ::: "memory");  // Q drained: vmcnt counts stages only

  __bf16* Pw = &Plds[wid][0];
  const int b = bh >> 4, h = bh & 15;
  int q0w = q0A;

  f32x4 acc[4] = {};
  float m = -__builtin_inff(), l = 0.f;

#define STAGE(IT, BUF)                                                                          \
  do {                                                                                          \
    __builtin_amdgcn_global_load_lds((gvoid_t*)(Kb + (size_t)((IT)*64 + r8) * 128 + scol),      \
                                     (lvoid_t*)((char*)Klds[BUF] + wid * 1024), 16, 0, 0);      \
    __builtin_amdgcn_global_load_lds((gvoid_t*)(Kb + (size_t)((IT)*64 + 32 + r8) * 128 + scol), \
                                     (lvoid_t*)((char*)Klds[BUF] + 4096 + wid * 1024), 16, 0, 0);\
    __builtin_amdgcn_global_load_lds((gvoid_t*)(vrow0 + (IT)*128),                              \
                                     (lvoid_t*)((char*)Vlds[BUF] + wid * 1024), 16, 0, 0);      \
    __builtin_amdgcn_global_load_lds((gvoid_t*)(vrow1 + (IT)*128),                              \
                                     (lvoid_t*)((char*)Vlds[BUF] + 4096 + wid * 1024), 16, 0, 0);\
  } while (0)

  STAGE(0, 0);
  STAGE((uA < 1) ? 0 : 1, 1);

  for (int u = 0; u < NU; ++u) {
    if (u < NU - 1) asm volatile("s_waitcnt vmcnt(8)" ::: "memory");
    else            asm volatile("s_waitcnt vmcnt(0)" ::: "memory");
    __builtin_amdgcn_sched_barrier(0);
    __builtin_amdgcn_s_barrier();            // unit u staged everywhere; u-1 compute done
    __builtin_amdgcn_sched_barrier(0);
    if (u + 2 < NU) {
      const int w2 = u + 2;
      const int itS = (w2 > uA) ? (w2 - uA - 1) : w2;
      STAGE(itS, w2 & 3);
    }
    __builtin_amdgcn_sched_barrier(0);

    const int it = (u > uA) ? (u - uA - 1) : u;
    const char* Kl = (const char*)Klds[u & 3];
    const char* Vl = (const char*)Vlds[u & 3];
    bf16x8s kf0[4], kf1[4];
#pragma unroll
    for (int ct = 0; ct < 4; ++ct) {
      const int rb = (ct * 16 + lr) * 128;
      kf0[ct] = *(const bf16x8s*)(Kl + rb + ((lg * 16) ^ ksw));
      kf1[ct] = *(const bf16x8s*)(Kl + rb + ((64 | (lg * 16)) ^ ksw));
    }
    f32x4 z[4];
    __builtin_amdgcn_s_setprio(1);
#pragma unroll
    for (int ct = 0; ct < 4; ++ct) {
      f32x4 t = {};
      t = __builtin_amdgcn_mfma_f32_16x16x32_bf16(kf0[ct], qc0, t, 0, 0, 0);
      z[ct] = __builtin_amdgcn_mfma_f32_16x16x32_bf16(kf1[ct], qc1, t, 0, 0, 0);
    }
    __builtin_amdgcn_s_setprio(0);

    const bool fin = (u == uA) || (u == NU - 1);  // diagonal unit == finalize unit
    float pv[4][4];
    float mx = -__builtin_inff();
    if (fin) {
      const int kv0 = it * 64;
#pragma unroll
      for (int ct = 0; ct < 4; ++ct)
#pragma unroll
        for (int j = 0; j < 4; ++j) {
          float v = z[ct][j];
          if (kv0 + ct * 16 + lg * 4 + j > q0w + lr) v = -__builtin_inff();
          pv[ct][j] = v;
          mx = fmaxf(mx, v);
        }
    } else {
#pragma unroll
      for (int ct = 0; ct < 4; ++ct)
#pragma unroll
        for (int j = 0; j < 4; ++j) {
          pv[ct][j] = z[ct][j];
          mx = fmaxf(mx, z[ct][j]);
        }
    }
    mx = fmaxf(mx, __shfl_xor(mx, 16));
    mx = fmaxf(mx, __shfl_xor(mx, 32));
    if (!__all(mx - m <= 8.f)) {  // defer-max
      const float mnew = fmaxf(m, mx);
      const float alpha = exp2f(m - mnew);
      f32x4 ab;
#pragma unroll
      for (int j = 0; j < 4; ++j) ab[j] = __shfl(alpha, lg * 4 + j);
#pragma unroll
      for (int nt2 = 0; nt2 < 4; ++nt2) acc[nt2] *= ab;
      l *= alpha;
      m = mnew;
    }
    float rs = 0.f;
#pragma unroll
    for (int ct = 0; ct < 4; ++ct)
#pragma unroll
      for (int j = 0; j < 4; ++j) {
        const float e = exp2f(pv[ct][j] - m);
        pv[ct][j] = e;
        rs += e;
      }
    rs += __shfl_xor(rs, 16);
    rs += __shfl_xor(rs, 32);
    l += rs;
#pragma unroll
    for (int ct = 0; ct < 4; ++ct) {
      bf16x4 pb;
#pragma unroll
      for (int j = 0; j < 4; ++j) pb[j] = (__bf16)pv[ct][j];
      *(bf16x4*)(Pw + lr * 72 + ct * 16 + lg * 4) = pb;
    }
    __builtin_amdgcn_s_setprio(1);
#pragma unroll
    for (int kc = 0; kc < 2; ++kc) {
      const bf16x8s pa = *(const bf16x8s*)(Pw + lr * 72 + kc * 32 + lg * 8);
#pragma unroll
      for (int nt2 = 0; nt2 < 4; ++nt2) {
        const bf16x8s vf = *(const bf16x8s*)(
            Vl + (nt2 * 16 + lr) * 128 + (((kc << 6) | (lg * 16)) ^ ksw));
        acc[nt2] = __builtin_amdgcn_mfma_f32_16x16x32_bf16(pa, vf, acc[nt2], 0, 0, 0);
      }
    }
    __builtin_amdgcn_s_setprio(0);

    if (fin) {  // write O for this q-tile, reset state, switch to phase-B Q
      const float linv = 1.f / l;
#pragma unroll
      for (int j = 0; j < 4; ++j) {
        const float iv = __shfl(linv, lg * 4 + j);
        const int t = q0w + lg * 4 + j;
        __bf16* dst = O + ((size_t)b * Tc + t) * Dc + h * HDc;
#pragma unroll
        for (int nt2 = 0; nt2 < 4; ++nt2) dst[nt2 * 16 + lr] = (__bf16)(acc[nt2][j] * iv);
      }
#pragma unroll
      for (int nt2 = 0; nt2 < 4; ++nt2) acc[nt2] = f32x4{0.f, 0.f, 0.f, 0.f};
      m = -__builtin_inff();
      l = 0.f;
      qc0 = qB0; qc1 = qB1; q0w = q0B;
    }
  }
#undef STAGE
}

// ---------------- launch ----------------
extern "C" void kernel_launch(void* const* d_in, const int* in_sizes, int n_in,
                              void* d_out, int out_size, void* d_ws, size_t ws_size,
                              hipStream_t stream) {
  const float* x   = (const float*)d_in[0];
  const float* cbt = (const float*)d_in[1];
  const float* sbt = (const float*)d_in[2];
  const float* Wq  = (const float*)d_in[3];
  const float* Wk  = (const float*)d_in[4];
  const float* Wv  = (const float*)d_in[5];
  const float* Wp  = (const float*)d_in[6];
  float* out = (float*)d_out;
  char* ws = (char*)d_ws;
  __bf16* xb = (__bf16*)(ws);
  __bf16* wb = (__bf16*)(ws + (8u << 20));
  __bf16* qb = (__bf16*)(ws + (16u << 20));
  __bf16* vt = (__bf16*)(ws + (40u << 20));
  __bf16* ao = (__bf16*)(ws + (48u << 20));
  __bf16* kb = qb + (size_t)Mc * Dc;

  cvt_all<<<8192, 256, 0, stream>>>(x, Wq, Wk, Wv, Wp, xb, wb);
  gemm_qkv<<<dim3(8, 32, 3), 256, 0, stream>>>(xb, wb, qb, vt, cbt, sbt);
  attn_kernel<<<512, 256, 0, stream>>>(qb, kb, vt, ao);
  gemm_proj<<<dim3(16, 32), 256, 0, stream>>>(ao, wb + 3u * (Dc * Dc), out);
}

// Round 6
// 105.934 us; speedup vs baseline: 2.9953x; 1.1071x over previous
//
#include <hip/hip_runtime.h>
#include <hip/hip_bf16.h>

typedef __attribute__((ext_vector_type(8))) short bf16x8s;   // 8 bf16 as shorts (MFMA frag)
typedef __attribute__((ext_vector_type(4))) float f32x4;
typedef __attribute__((ext_vector_type(4))) __bf16 bf16x4;
typedef __attribute__((ext_vector_type(8))) __bf16 bf16x8;

typedef const __attribute__((address_space(1))) void gvoid_t;
typedef __attribute__((address_space(3))) void lvoid_t;

constexpr int Bc = 2, Tc = 2048, Dc = 1024, Hc = 16, HDc = 64;
constexpr int Mc = Bc * Tc;  // 4096

// ---------------- fused fp32 -> bf16 convert: x (4096 blocks) + 4 weights (4096) ----
__global__ void cvt_all(const float* __restrict__ x,
                        const float* __restrict__ wq, const float* __restrict__ wk,
                        const float* __restrict__ wv, const float* __restrict__ wp,
                        __bf16* __restrict__ xb, __bf16* __restrict__ wb) {
  const int bid = blockIdx.x;
  const float* src;
  __bf16* dst;
  int i;
  if (bid < 4096) {
    src = x; dst = xb; i = (bid * 256 + threadIdx.x) * 4;
  } else {
    const int r = bid - 4096;
    const int w = r >> 10;
    src = (w == 0) ? wq : (w == 1) ? wk : (w == 2) ? wv : wp;
    dst = wb + (size_t)w * (Dc * Dc);
    i = ((r & 1023) * 256 + threadIdx.x) * 4;
  }
  float4 v = *(const float4*)(src + i);
  bf16x4 o;
  o[0] = (__bf16)v.x; o[1] = (__bf16)v.y; o[2] = (__bf16)v.z; o[3] = (__bf16)v.w;
  *(bf16x4*)(dst + i) = o;
}

// ---------------- QKV GEMM: C[m][e] = sum_d A[m][d] * W[e][d] ----------------------
// z=0: RoPE+score-scale -> [B,H,T,HD]; z=1: RoPE -> [B,H,T,HD];
// z=2: V^T epilogue (LDS transpose bounce) -> vt [B,H,HD,T]
__launch_bounds__(256, 2)
__global__ void gemm_qkv(const __bf16* __restrict__ A,
                         const __bf16* __restrict__ W,
                         __bf16* __restrict__ outb,
                         __bf16* __restrict__ vtout,
                         const float* __restrict__ cbt,
                         const float* __restrict__ sbt) {
  __shared__ __bf16 smem[2][128 * 64];
  __bf16* Alds = smem[0];
  __bf16* Blds = smem[1];
  const int tid = threadIdx.x;
  const int lane = tid & 63, wid = tid >> 6;
  const int wr = wid >> 1, wc = wid & 1;
  const int lr = lane & 15, lg = lane >> 4;
  // XCD-chunked remap: each XCD owns 4 M-rows x 8 N-cols (1MB A + 2MB B in its L2)
  const int lid = blockIdx.x + (int)gridDim.x * blockIdx.y;
  const int xcd = lid & 7, g = lid >> 3;
  const int brow = (xcd * 4 + (g & 3)) * 128;
  const int bcol = (g >> 2) * 128;
  const __bf16* Wm = W + (size_t)blockIdx.z * (Dc * Dc);

  f32x4 acc[4][4] = {};

  const char* Ag = (const char*)(A + (size_t)brow * Dc);
  const char* Bg = (const char*)(Wm + (size_t)bcol * Dc);
  const int r0 = tid >> 3;
  const int cb = (tid & 7) * 16;

  for (int k0 = 0; k0 < Dc; k0 += 64) {
#pragma unroll
    for (int i = 0; i < 4; ++i) {
      const int r = i * 32 + r0;
      const int ldsoff = (i * 256 + wid * 64) * 16;
      __builtin_amdgcn_global_load_lds(
          (gvoid_t*)(Ag + (size_t)r * (Dc * 2) + k0 * 2 + cb),
          (lvoid_t*)((char*)Alds + ldsoff), 16, 0, 0);
      __builtin_amdgcn_global_load_lds(
          (gvoid_t*)(Bg + (size_t)r * (Dc * 2) + k0 * 2 + cb),
          (lvoid_t*)((char*)Blds + ldsoff), 16, 0, 0);
    }
    __syncthreads();
#pragma unroll
    for (int kk = 0; kk < 2; ++kk) {
      const int col = kk * 32 + lg * 8;
      bf16x8s af[4], bfv[4];
#pragma unroll
      for (int m = 0; m < 4; ++m)
        af[m] = *(const bf16x8s*)(Alds + (wr * 64 + m * 16 + lr) * 64 + col);
#pragma unroll
      for (int n = 0; n < 4; ++n)
        bfv[n] = *(const bf16x8s*)(Blds + (wc * 64 + n * 16 + lr) * 64 + col);
#pragma unroll
      for (int m = 0; m < 4; ++m)
#pragma unroll
        for (int n = 0; n < 4; ++n)
          acc[m][n] = __builtin_amdgcn_mfma_f32_16x16x32_bf16(af[m], bfv[n], acc[m][n], 0, 0, 0);
    }
    __syncthreads();
  }

  const int z = blockIdx.z;
  if (z == 2) {
    // V^T epilogue: stage C^T halves in LDS, coalesced store to vt [B,H,HD,T]
    const int bb = brow >> 11, t0b = brow & (Tc - 1);
    __bf16* tile_t = smem[0];  // [64][136]
#pragma unroll
    for (int h2 = 0; h2 < 2; ++h2) {
      __syncthreads();
      if (wc == h2) {
#pragma unroll
        for (int n = 0; n < 4; ++n) {
#pragma unroll
          for (int m = 0; m < 4; ++m) {
            bf16x4 pb;
#pragma unroll
            for (int j = 0; j < 4; ++j) pb[j] = (__bf16)acc[m][n][j];
            *(bf16x4*)(tile_t + (n * 16 + lr) * 136 + wr * 64 + m * 16 + lg * 4) = pb;
          }
        }
      }
      __syncthreads();
#pragma unroll
      for (int pass = 0; pass < 4; ++pass) {
        const int r = pass * 16 + (tid >> 4);
        const int c8 = (tid & 15) * 8;
        bf16x8 vvv = *(const bf16x8*)(tile_t + r * 136 + c8);
        const int gn = bcol + h2 * 64 + r;
        const int h = gn >> 6, hd = gn & 63;
        *(bf16x8*)(vtout + (((size_t)bb * Hc + h) * HDc + hd) * Tc + t0b + c8) = vvv;
      }
    }
    return;
  }

  // z==0/1: fused RoPE (+ score scale for Q), scatter to [B,H,T,HD]
  {
    const float scl = (z == 0) ? 0.18033688011112042f : 1.0f;  // (1/8)*log2(e)
#pragma unroll
    for (int m = 0; m < 4; ++m) {
#pragma unroll
      for (int j = 0; j < 4; ++j) {
        const int gm = brow + wr * 64 + m * 16 + lg * 4 + j;
        const float* cbase = cbt + (size_t)gm * HDc;
        const float* sbase = sbt + (size_t)gm * HDc;
#pragma unroll
        for (int n = 0; n < 2; ++n) {
          const int i = n * 16 + lr;
          const float c0 = cbase[i], s0 = sbase[i];
          const float c1 = cbase[i + 32], s1 = sbase[i + 32];
          const float v0 = acc[m][n][j], v1 = acc[m][n + 2][j];
          acc[m][n][j]     = (v0 * c0 - v1 * s0) * scl;
          acc[m][n + 2][j] = (v1 * c1 + v0 * s1) * scl;
        }
      }
    }
    __bf16* dst = outb + (size_t)z * ((size_t)Mc * Dc);
#pragma unroll
    for (int m = 0; m < 4; ++m) {
#pragma unroll
      for (int j = 0; j < 4; ++j) {
        const int gm = brow + wr * 64 + m * 16 + lg * 4 + j;
        const int bb = gm >> 11, t = gm & (Tc - 1);
#pragma unroll
        for (int n = 0; n < 4; ++n) {
          const int gn = bcol + wc * 64 + n * 16 + lr;
          const int h = gn >> 6, hd = gn & 63;
          dst[(((size_t)bb * Hc + h) * Tc + t) * HDc + hd] = (__bf16)acc[m][n][j];
        }
      }
    }
  }
}

// ---------------- output projection GEMM: 128x64 tiles, 512 blocks (2/CU) ----------
__launch_bounds__(256, 2)
__global__ void gemm_proj(const __bf16* __restrict__ A, const __bf16* __restrict__ W,
                          float* __restrict__ outf) {
  __shared__ __bf16 Alds[128 * 64];
  __shared__ __bf16 Blds[64 * 64];
  const int tid = threadIdx.x;
  const int lane = tid & 63, wid = tid >> 6;
  const int lr = lane & 15, lg = lane >> 4;
  const int lid = blockIdx.x + (int)gridDim.x * blockIdx.y;  // 512 blocks
  const int xcd = lid & 7, g = lid >> 3;
  const int brow = (xcd * 4 + (g & 3)) * 128;
  const int bcol = (g >> 2) * 64;
  f32x4 acc[2][4] = {};
  const char* Ag = (const char*)(A + (size_t)brow * Dc);
  const char* Bg = (const char*)(W + (size_t)bcol * Dc);
  const int r0 = tid >> 3;
  const int cb = (tid & 7) * 16;
  for (int k0 = 0; k0 < Dc; k0 += 64) {
#pragma unroll
    for (int i = 0; i < 4; ++i) {
      const int r = i * 32 + r0;
      const int ldsoff = (i * 256 + wid * 64) * 16;
      __builtin_amdgcn_global_load_lds(
          (gvoid_t*)(Ag + (size_t)r * (Dc * 2) + k0 * 2 + cb),
          (lvoid_t*)((char*)Alds + ldsoff), 16, 0, 0);
    }
#pragma unroll
    for (int i = 0; i < 2; ++i) {
      const int r = i * 32 + r0;
      const int ldsoff = (i * 256 + wid * 64) * 16;
      __builtin_amdgcn_global_load_lds(
          (gvoid_t*)(Bg + (size_t)r * (Dc * 2) + k0 * 2 + cb),
          (lvoid_t*)((char*)Blds + ldsoff), 16, 0, 0);
    }
    __syncthreads();
#pragma unroll
    for (int kk = 0; kk < 2; ++kk) {
      const int col = kk * 32 + lg * 8;
      bf16x8s af[2], bfv[4];
#pragma unroll
      for (int m = 0; m < 2; ++m)
        af[m] = *(const bf16x8s*)(Alds + (wid * 32 + m * 16 + lr) * 64 + col);
#pragma unroll
      for (int n = 0; n < 4; ++n)
        bfv[n] = *(const bf16x8s*)(Blds + (n * 16 + lr) * 64 + col);
#pragma unroll
      for (int m = 0; m < 2; ++m)
#pragma unroll
        for (int n = 0; n < 4; ++n)
          acc[m][n] = __builtin_amdgcn_mfma_f32_16x16x32_bf16(af[m], bfv[n], acc[m][n], 0, 0, 0);
    }
    __syncthreads();
  }
#pragma unroll
  for (int m = 0; m < 2; ++m)
#pragma unroll
    for (int j = 0; j < 4; ++j) {
      const int gm = brow + wid * 32 + m * 16 + lg * 4 + j;
#pragma unroll
      for (int n = 0; n < 4; ++n) {
        const int gn = bcol + n * 16 + lr;
        outf[(size_t)gm * Dc + gn] = acc[m][n][j];
      }
    }
}

// ---------------- causal flash attention (v6: KVBLK=128, 17 units) ----------------
// 64-row q-tiles, balanced pairs (p, 31-p): ceil((p+1)/2)+ceil((32-p)/2) = 17
// 128-KV units for EVERY block. K [128kv][64hd] + V^T [64hd][128kv] double-
// buffered in LDS (XOR-swizzled; K key row&7, V key row&15), depth-1 prefetch,
// ONE s_barrier + one vmcnt(0) per unit (prefetch has a whole unit to land).
// Only the last unit of each phase is masked (= finalize unit). P-LDS reused
// per 64-kv half. XCD-grouped bh mapping (4 bh per XCD -> K/V L2-resident).
__launch_bounds__(256, 2)
__global__ void attn_kernel(const __bf16* __restrict__ Q, const __bf16* __restrict__ K,
                            const __bf16* __restrict__ Vt, __bf16* __restrict__ O) {
  __shared__ __bf16 Klds[2][128 * 64];   // [kv][hd], rows 128B
  __shared__ __bf16 Vlds[2][64 * 128];   // [hd][kv], rows 256B
  __shared__ __bf16 Plds[4][16 * 72];    // per-wave 16x64 P half-tile
  const int f = blockIdx.x;
  const int xcd = f & 7, g = f >> 3;     // 64 blocks per XCD = 4 bh
  const int bh = xcd * 4 + (g >> 4);
  const int p = g & 15;                  // pair: q-tiles p and 31-p
  const int tid = threadIdx.x;
  const int lane = tid & 63, wid = tid >> 6;
  const int lr = lane & 15, lg = lane >> 4;
  const __bf16* Qp = Q + (size_t)bh * Tc * HDc;
  const char* Kb = (const char*)(K + (size_t)bh * Tc * HDc);
  const char* Vb = (const char*)(Vt + (size_t)bh * HDc * Tc);

  const int qtB = 31 - p;
  const int unitsA = (p + 2) >> 1;
  const int NU = 17;

  // K staging: wave covers kv rows [wid*32, +32), instr i rows +i*8, lane>>3
  const int krow = wid * 32 + (lane >> 3);
  const int kssw = (((lane & 7) ^ ((lane >> 3) & 7)) << 4);  // pre-swizzled src col
  // V staging: wave covers hd rows [wid*16, +16), instr i rows +i*4, lane>>4
  const int vrow = wid * 16 + lg;
  const int ksw = lr & 7;                 // QK read swizzle key

  const int q0A = p * 64 + wid * 16, q0B = qtB * 64 + wid * 16;
  bf16x8s qc0 = *(const bf16x8s*)(Qp + (q0A + lr) * HDc + lg * 8);
  bf16x8s qc1 = *(const bf16x8s*)(Qp + (q0A + lr) * HDc + 32 + lg * 8);
  const bf16x8s qB0 = *(const bf16x8s*)(Qp + (q0B + lr) * HDc + lg * 8);
  const bf16x8s qB1 = *(const bf16x8s*)(Qp + (q0B + lr) * HDc + 32 + lg * 8);

  __bf16* Pw = &Plds[wid][0];
  const int b = bh >> 4, h = bh & 15;
  int q0w = q0A;

  f32x4 acc[4] = {};
  float m = -__builtin_inff(), l = 0.f;

#define STAGE(IT, BUF)                                                                    \
  do {                                                                                    \
    _Pragma("unroll")                                                                     \
    for (int i_ = 0; i_ < 4; ++i_) {                                                      \
      __builtin_amdgcn_global_load_lds(                                                   \
          (gvoid_t*)(Kb + (size_t)((IT) * 128 + krow + i_ * 8) * 128 + kssw),             \
          (lvoid_t*)((char*)Klds[BUF] + wid * 4096 + i_ * 1024), 16, 0, 0);               \
      __builtin_amdgcn_global_load_lds(                                                   \
          (gvoid_t*)(Vb + (size_t)(vrow + i_ * 4) * (Tc * 2) + (IT) * 256 +               \
                     ((lr ^ ((lg + 4 * i_) & 15)) << 4)),                                 \
          (lvoid_t*)((char*)Vlds[BUF] + wid * 4096 + i_ * 1024), 16, 0, 0);               \
    }                                                                                     \
  } while (0)

  STAGE(0, 0);
  asm volatile("s_waitcnt vmcnt(0)" ::: "memory");
  __builtin_amdgcn_sched_barrier(0);
  __builtin_amdgcn_s_barrier();

  for (int u = 0; u < NU; ++u) {
    if (u + 1 < NU) {
      const int it1 = (u + 1 < unitsA) ? (u + 1) : (u + 1 - unitsA);
      STAGE(it1, (u + 1) & 1);
    }
    __builtin_amdgcn_sched_barrier(0);

    const int it = (u < unitsA) ? u : (u - unitsA);
    const int kv0 = it * 128;
    const char* Kl = (const char*)Klds[u & 1];
    const char* Vl = (const char*)Vlds[u & 1];

    // ---- QK^T over 128 kv (8 ct blocks, two 64-row halves) ----
    float pv[8][4];
#pragma unroll
    for (int hh = 0; hh < 2; ++hh) {
      bf16x8s kf0[4], kf1[4];
#pragma unroll
      for (int c4 = 0; c4 < 4; ++c4) {
        const int rb = (hh * 64 + c4 * 16 + lr) * 128;
        kf0[c4] = *(const bf16x8s*)(Kl + rb + ((lg ^ ksw) << 4));
        kf1[c4] = *(const bf16x8s*)(Kl + rb + (((4 | lg) ^ ksw) << 4));
      }
      __builtin_amdgcn_s_setprio(1);
#pragma unroll
      for (int c4 = 0; c4 < 4; ++c4) {
        f32x4 t = {};
        t = __builtin_amdgcn_mfma_f32_16x16x32_bf16(kf0[c4], qc0, t, 0, 0, 0);
        t = __builtin_amdgcn_mfma_f32_16x16x32_bf16(kf1[c4], qc1, t, 0, 0, 0);
#pragma unroll
        for (int j = 0; j < 4; ++j) pv[hh * 4 + c4][j] = t[j];
      }
      __builtin_amdgcn_s_setprio(0);
    }

    const bool fin = (u == unitsA - 1) || (u == NU - 1);  // diagonal == finalize
    float mx = -__builtin_inff();
    if (fin) {
#pragma unroll
      for (int ct = 0; ct < 8; ++ct)
#pragma unroll
        for (int j = 0; j < 4; ++j) {
          float v = pv[ct][j];
          if (kv0 + ct * 16 + lg * 4 + j > q0w + lr) v = -__builtin_inff();
          pv[ct][j] = v;
          mx = fmaxf(mx, v);
        }
    } else {
#pragma unroll
      for (int ct = 0; ct < 8; ++ct)
#pragma unroll
        for (int j = 0; j < 4; ++j) mx = fmaxf(mx, pv[ct][j]);
    }
    mx = fmaxf(mx, __shfl_xor(mx, 16));
    mx = fmaxf(mx, __shfl_xor(mx, 32));
    if (!__all(mx - m <= 8.f)) {  // defer-max: rescale only on real growth
      const float mnew = fmaxf(m, mx);
      const float alpha = __builtin_amdgcn_exp2f(m - mnew);
      f32x4 ab;
#pragma unroll
      for (int j = 0; j < 4; ++j) ab[j] = __shfl(alpha, lg * 4 + j);
#pragma unroll
      for (int nt2 = 0; nt2 < 4; ++nt2) acc[nt2] *= ab;
      l *= alpha;
      m = mnew;
    }
    float rs = 0.f;
#pragma unroll
    for (int ct = 0; ct < 8; ++ct)
#pragma unroll
      for (int j = 0; j < 4; ++j) {
        const float e = __builtin_amdgcn_exp2f(pv[ct][j] - m);
        pv[ct][j] = e;
        rs += e;
      }
    rs += __shfl_xor(rs, 16);
    rs += __shfl_xor(rs, 32);
    l += rs;

    // ---- PV over 128 kv, two 64-kv halves sharing the P-LDS region ----
#pragma unroll
    for (int hh = 0; hh < 2; ++hh) {
#pragma unroll
      for (int c4 = 0; c4 < 4; ++c4) {
        bf16x4 pb;
#pragma unroll
        for (int j = 0; j < 4; ++j) pb[j] = (__bf16)pv[hh * 4 + c4][j];
        *(bf16x4*)(Pw + lr * 72 + c4 * 16 + lg * 4) = pb;
      }
      __builtin_amdgcn_s_setprio(1);
#pragma unroll
      for (int kc = 0; kc < 2; ++kc) {
        const bf16x8s pa = *(const bf16x8s*)(Pw + lr * 72 + kc * 32 + lg * 8);
#pragma unroll
        for (int nt2 = 0; nt2 < 4; ++nt2) {
          const bf16x8s vf = *(const bf16x8s*)(
              Vl + (nt2 * 16 + lr) * 256 + (((hh * 8 + kc * 4 + lg) ^ lr) << 4));
          acc[nt2] = __builtin_amdgcn_mfma_f32_16x16x32_bf16(pa, vf, acc[nt2], 0, 0, 0);
        }
      }
      __builtin_amdgcn_s_setprio(0);
    }

    if (fin) {  // write O for this q-tile, reset state, switch to phase-B Q
      const float linv = 1.f / l;
#pragma unroll
      for (int j = 0; j < 4; ++j) {
        const float iv = __shfl(linv, lg * 4 + j);
        const int t = q0w + lg * 4 + j;
        __bf16* dst = O + ((size_t)b * Tc + t) * Dc + h * HDc;
#pragma unroll
        for (int nt2 = 0; nt2 < 4; ++nt2) dst[nt2 * 16 + lr] = (__bf16)(acc[nt2][j] * iv);
      }
#pragma unroll
      for (int nt2 = 0; nt2 < 4; ++nt2) acc[nt2] = f32x4{0.f, 0.f, 0.f, 0.f};
      m = -__builtin_inff();
      l = 0.f;
      qc0 = qB0; qc1 = qB1; q0w = q0B;
    }

    if (u + 1 < NU) {
      asm volatile("s_waitcnt vmcnt(0)" ::: "memory");  // stage(u+1) landed
      __builtin_amdgcn_sched_barrier(0);
      __builtin_amdgcn_s_barrier();  // all waves done with buf[u&1]; buf[(u+1)&1] ready
      __builtin_amdgcn_sched_barrier(0);
    }
  }
#undef STAGE
}

// ---------------- launch ----------------
extern "C" void kernel_launch(void* const* d_in, const int* in_sizes, int n_in,
                              void* d_out, int out_size, void* d_ws, size_t ws_size,
                              hipStream_t stream) {
  const float* x   = (const float*)d_in[0];
  const float* cbt = (const float*)d_in[1];
  const float* sbt = (const float*)d_in[2];
  const float* Wq  = (const float*)d_in[3];
  const float* Wk  = (const float*)d_in[4];
  const float* Wv  = (const float*)d_in[5];
  const float* Wp  = (const float*)d_in[6];
  float* out = (float*)d_out;
  char* ws = (char*)d_ws;
  __bf16* xb = (__bf16*)(ws);
  __bf16* wb = (__bf16*)(ws + (8u << 20));
  __bf16* qb = (__bf16*)(ws + (16u << 20));
  __bf16* vt = (__bf16*)(ws + (40u << 20));
  __bf16* ao = (__bf16*)(ws + (48u << 20));
  __bf16* kb = qb + (size_t)Mc * Dc;

  cvt_all<<<8192, 256, 0, stream>>>(x, Wq, Wk, Wv, Wp, xb, wb);
  gemm_qkv<<<dim3(8, 32, 3), 256, 0, stream>>>(xb, wb, qb, vt, cbt, sbt);
  attn_kernel<<<512, 256, 0, stream>>>(qb, kb, vt, ao);
  gemm_proj<<<dim3(16, 32), 256, 0, stream>>>(ao, wb + 3u * (Dc * Dc), out);
}